// Round 12
// baseline (262.044 us; speedup 1.0000x reference)
//
#include <hip/hip_runtime.h>
#include <hip/hip_bf16.h>

#define N_NODES 100000
#define N_EDGES 1000000
#define EMB 64
#define HID 64
#define VOCAB 128
#define N_GRAPHS 2048

#define CBUCKET 1024                                   // nodes per bucket
#define NBK ((N_NODES + CBUCKET - 1) / CBUCKET)        // 98
#define CAP 16384                                      // slots per bucket (E[cnt]=10204)
#define CHUNK 4096
#define SCAT_BLOCKS ((N_EDGES + CHUNK - 1) / CHUNK)    // 245
#define GB ((N_NODES + 255) / 256)                     // 391 gstart blocks

#define BCASTF(v, l) __int_as_float(__builtin_amdgcn_readlane(__float_as_int(v), (l)))

typedef __attribute__((ext_vector_type(8))) short short8;
typedef __attribute__((ext_vector_type(4))) float f32x4;

__device__ __forceinline__ float bf2f(unsigned short u) {
    return __uint_as_float((unsigned)u << 16);
}
__device__ __forceinline__ unsigned short f2bf(float f) {
    return __bfloat16_as_ushort(__float2bfloat16(f));
}

// ---- fused setup: gstart (blocks 0..GB-1) + precompute (GB..GB+31) + init --
__global__ __launch_bounds__(256) void setup_kernel(
    const int* __restrict__ batch, int* __restrict__ gstart,
    const float* __restrict__ emb, const float* __restrict__ W1l,
    const float* __restrict__ W1r,
    const float* __restrict__ W2l, const float* __restrict__ W2r,
    float* __restrict__ embW1l, float* __restrict__ embW1r,
    unsigned short* __restrict__ w2frag,
    int* __restrict__ cursor, float* __restrict__ gsum)
{
    int b = blockIdx.x;
    int t = threadIdx.x;
    if (b < GB) {
        // graph boundaries (batch sorted)
        int i = b * 256 + t;
        if (i >= N_NODES) return;
        int bg = batch[i];
        int bp = (i == 0) ? -1 : batch[i - 1];
        for (int g = bp + 1; g <= bg; ++g) gstart[g] = i;
        if (i == N_NODES - 1)
            for (int g = bg + 1; g <= N_GRAPHS; ++g) gstart[g] = N_NODES;
    } else if (b < GB + 32) {
        int vb = b - GB;
        int wave = t >> 6, lane = t & 63;
        int v = vb * 4 + wave;
        if (v < VOCAB) {
            float er = emb[v * 64 + lane];       // lane = d
            float al = 0.f, ar = 0.f;
#pragma unroll 8
            for (int d = 0; d < 64; ++d) {
                float e = BCASTF(er, d);
                al += e * W1l[d * 64 + lane];
                ar += e * W1r[d * 64 + lane];
            }
            embW1l[v * 64 + lane] = al;
            embW1r[v * 64 + lane] = ar;
        }
        // W2 B-fragment packing: g = tt*1024 + h*512 + l*8 + j
        int g = vb * 256 + t;
        int j = g & 7, l = (g >> 3) & 63, h = (g >> 9) & 1, tt = g >> 10;
        int k = h * 32 + ((l >> 4) * 8) + j;
        int n = tt * 16 + (l & 15);
        float w = (n < 64) ? W2l[k * 64 + n] : W2r[k * 64 + (n - 64)];
        w2frag[g] = f2bf(w);
    } else {
        if (t < NBK) cursor[t] = t * CAP;
        for (int i = t; i < N_GRAPHS * 2; i += 256) gsum[i] = 0.f;
    }
}

// ---- scatter: LDS-staged chunk, per-(block,bucket) run reservation ----
__global__ __launch_bounds__(256) void scatter_kernel(
    const int* __restrict__ src, const int* __restrict__ dst,
    int* __restrict__ cursor, unsigned* __restrict__ edge8)
{
    __shared__ unsigned earr[CHUNK];        // 16 KB packed payload
    __shared__ unsigned char karr[CHUNK];   // 4 KB bucket key
    __shared__ int bcnt[NBK];
    __shared__ int bbase[NBK];
    int t = threadIdx.x;
    if (t < NBK) bcnt[t] = 0;
    __syncthreads();
    int e0 = blockIdx.x * CHUNK;
    int n = min(e0 + CHUNK, N_EDGES) - e0;
    for (int i = t; i < n; i += 256) {
        int d = dst[e0 + i];
        int s = src[e0 + i];
        int k = d >> 10;
        earr[i] = (unsigned)s | ((unsigned)(d & 1023) << 17);   // src < 2^17
        karr[i] = (unsigned char)k;
        atomicAdd(&bcnt[k], 1);
    }
    __syncthreads();
    if (t < NBK) {
        int c = bcnt[t];
        bbase[t] = c ? atomicAdd(&cursor[t], c) : 0;
        bcnt[t] = 0;                        // reuse as local cursor
    }
    __syncthreads();
    for (int i = t; i < n; i += 256) {
        int k = karr[i];
        int off = atomicAdd(&bcnt[k], 1);
        edge8[bbase[k] + off] = earr[i];    // dense single-writer runs
    }
}

// ---- per-bucket CSR build (rowstart/deg/col), dense writes ------
__global__ __launch_bounds__(256) void csr_kernel(
    const unsigned* __restrict__ edge8, const int* __restrict__ cursor,
    int* __restrict__ row_start, int* __restrict__ deg, int* __restrict__ col)
{
    __shared__ int cnt[CBUCKET];
    __shared__ int ssum[256];
    int b = blockIdx.x;                   // NBK blocks
    int t = threadIdx.x;
    int lo = b * CAP, hi = cursor[b];     // cursor holds final fill level
    for (int i = t; i < CBUCKET; i += 256) cnt[i] = 0;
    __syncthreads();
    for (int i = lo + t; i < hi; i += 256)
        atomicAdd(&cnt[edge8[i] >> 17], 1);
    __syncthreads();
    int v[4]; int sum = 0;
#pragma unroll
    for (int i = 0; i < 4; ++i) { v[i] = cnt[t * 4 + i]; sum += v[i]; }
    ssum[t] = sum;
    __syncthreads();
    for (int off = 1; off < 256; off <<= 1) {
        int tmp = (t >= off) ? ssum[t - off] : 0;
        __syncthreads();
        ssum[t] += tmp;
        __syncthreads();
    }
    int run = ssum[t] - sum;
    int ex0 = run, ex1 = ex0 + v[0], ex2 = ex1 + v[1], ex3 = ex2 + v[2];
    int node = b * CBUCKET + t * 4;
    if (node + 3 < N_NODES) {
        *(int4*)&row_start[node] = make_int4(lo + ex0, lo + ex1, lo + ex2, lo + ex3);
        *(int4*)&deg[node]       = make_int4(v[0], v[1], v[2], v[3]);
    } else {
        int ex[4] = {ex0, ex1, ex2, ex3};
        for (int i = 0; i < 4; ++i)
            if (node + i < N_NODES) { row_start[node + i] = lo + ex[i]; deg[node + i] = v[i]; }
    }
    cnt[t * 4 + 0] = ex0; cnt[t * 4 + 1] = ex1;       // reuse as cursors
    cnt[t * 4 + 2] = ex2; cnt[t * 4 + 3] = ex3;
    __syncthreads();
    for (int i = lo + t; i < hi; i += 256) {
        unsigned e = edge8[i];
        int slot = atomicAdd(&cnt[e >> 17], 1);
        col[lo + slot] = (int)(e & 0x1FFFF);          // dense ~40 KB window
    }
}

// ---- layer 1 (lean): h1 = relu(mean_j(embW1l[x_j]) + b1 + embW1r[x_i]) ----
#define S1_NPW 8
__global__ __launch_bounds__(256) void sage1_kernel(
    const int* __restrict__ x, const float* __restrict__ embW1l,
    const float* __restrict__ embW1r, const float* __restrict__ b1,
    const int* __restrict__ row_start, const int* __restrict__ deg,
    const int* __restrict__ col, unsigned short* __restrict__ h1b)
{
    __shared__ float elds[VOCAB * 64];      // 32 KB -> 5 blocks/CU
    int t = threadIdx.x;
    for (int i = t * 4; i < VOCAB * 64; i += 1024)
        *(float4*)&elds[i] = *(const float4*)&embW1l[i];
    __syncthreads();

    int wave = t >> 6, lane = t & 63;
    int base_node = (blockIdx.x * 4 + wave) * S1_NPW;   // 3125*32 = 100000 exact
    float bias = b1[lane];

    int rs[S1_NPW], dgs[S1_NPW], cidx[S1_NPW], xv[S1_NPW], xn[S1_NPW];
    float self[S1_NPW];
#pragma unroll
    for (int n = 0; n < S1_NPW; ++n) {
        rs[n] = row_start[base_node + n];
        dgs[n] = deg[base_node + n];
        xn[n] = x[base_node + n];
    }
#pragma unroll
    for (int n = 0; n < S1_NPW; ++n)
        cidx[n] = (lane < dgs[n]) ? col[rs[n] + lane] : 0;
#pragma unroll
    for (int n = 0; n < S1_NPW; ++n) {
        xv[n] = (lane < dgs[n]) ? x[cidx[n]] : 0;
        self[n] = embW1r[xn[n] * 64 + lane];
    }

    for (int n = 0; n < S1_NPW; ++n) {
        int node = base_node + n;
        int dg = dgs[n];
        int dgc = (dg < 64) ? dg : 64;

        float s0 = 0.f, s1 = 0.f, s2 = 0.f, s3 = 0.f;
        int j = 0;
        for (; j + 4 <= dgc; j += 4) {
            int x0 = __builtin_amdgcn_readlane(xv[n], j + 0);
            int x1 = __builtin_amdgcn_readlane(xv[n], j + 1);
            int x2 = __builtin_amdgcn_readlane(xv[n], j + 2);
            int x3 = __builtin_amdgcn_readlane(xv[n], j + 3);
            s0 += elds[x0 * 64 + lane];
            s1 += elds[x1 * 64 + lane];
            s2 += elds[x2 * 64 + lane];
            s3 += elds[x3 * 64 + lane];
        }
        for (; j < dgc; ++j) {
            int x0 = __builtin_amdgcn_readlane(xv[n], j);
            s0 += elds[x0 * 64 + lane];
        }
        for (int k = 64; k < dg; ++k) {                 // deg>64 tail (rare)
            int c = col[rs[n] + k];
            s0 += elds[x[c] * 64 + lane];
        }
        float mean = ((s0 + s1) + (s2 + s3)) / fmaxf((float)dg, 1.0f);
        h1b[node * 64 + lane] = f2bf(fmaxf(mean + bias + self[n], 0.f));
    }
}

// ---- MFMA transform: [p|q] = h1 @ [W2l|W2r]  (M=100000, N=128, K=64) ----
// p stored fp8 e4m3 (gathered later -> smaller working set), q stored bf16.
__global__ __launch_bounds__(256) void mfma_transform_kernel(
    const unsigned short* __restrict__ h1b,
    const unsigned short* __restrict__ w2frag,
    unsigned char* __restrict__ p8, unsigned short* __restrict__ q16)
{
    int wave = threadIdx.x >> 6, lane = threadIdx.x & 63;
    int base16 = blockIdx.x * 64 + wave * 16;
    if (base16 >= N_NODES) return;                      // tail waves only
    int m = lane & 15, quad = lane >> 4;

    const unsigned short* arow = h1b + (base16 + m) * 64 + quad * 8;
    short8 a0 = *(const short8*)(arow);                 // k = 0..31
    short8 a1 = *(const short8*)(arow + 32);            // k = 32..63

#pragma unroll
    for (int tt = 0; tt < 8; ++tt) {                    // 8 output tiles of 16
        short8 b0 = *(const short8*)(w2frag + (tt * 1024 + 0)   + lane * 8);
        short8 b1 = *(const short8*)(w2frag + (tt * 1024 + 512) + lane * 8);
        f32x4 acc = {0.f, 0.f, 0.f, 0.f};
        acc = __builtin_amdgcn_mfma_f32_16x16x32_bf16(a0, b0, acc, 0, 0, 0);
        acc = __builtin_amdgcn_mfma_f32_16x16x32_bf16(a1, b1, acc, 0, 0, 0);
        int o = tt * 16 + m;
        if (o < 64) {
            // p: pack to fp8 e4m3 (rows i, i+1 share a pk convert)
            int pk01 = __builtin_amdgcn_cvt_pk_fp8_f32(acc[0], acc[1], 0, false);
            int pk23 = __builtin_amdgcn_cvt_pk_fp8_f32(acc[2], acc[3], 0, false);
            p8[(base16 + quad * 4 + 0) * 64 + o] = (unsigned char)(pk01 & 0xff);
            p8[(base16 + quad * 4 + 1) * 64 + o] = (unsigned char)((pk01 >> 8) & 0xff);
            p8[(base16 + quad * 4 + 2) * 64 + o] = (unsigned char)(pk23 & 0xff);
            p8[(base16 + quad * 4 + 3) * 64 + o] = (unsigned char)((pk23 >> 8) & 0xff);
        } else {
            int oc = o & 63;
#pragma unroll
            for (int i = 0; i < 4; ++i) {
                int node = base16 + quad * 4 + i;
                q16[node * 64 + oc] = f2bf(acc[i]);
            }
        }
    }
}

// ---- gather v5: masked loads (no round-up transactions) + 2-stage pipeline,
//      4 nodes/wave, all first-iteration loads hoisted across node boundaries.
//   h2 = relu(mean_j p_j + b2 + q_i);  gsum[batch] += h2 @ Wout
#define S2_NPW 4
__global__ __launch_bounds__(256, 8) void sage2_kernel(
    const unsigned char* __restrict__ p, const unsigned short* __restrict__ q,
    const int* __restrict__ row_start, const int* __restrict__ deg,
    const int* __restrict__ col, const float* __restrict__ b2,
    const float* __restrict__ Wout, const int* __restrict__ batch,
    float* __restrict__ gsum)
{
    int t = threadIdx.x;
    int wave = t >> 6, lane = t & 63;
    int base_node = (blockIdx.x * 4 + wave) * S2_NPW;   // 6250*16 = 100000 exact
    int c = lane & 15;          // feature quad: features 4c..4c+3
    int g = lane >> 4;          // row group 0..3

    float4 b2v = ((const float4*)b2)[c];
    float4 w01 = ((const float4*)Wout)[c * 2];
    float4 w23 = ((const float4*)Wout)[c * 2 + 1];

    // prefetch per-node metadata + neighbor index rows for all 4 nodes
    int rs[S2_NPW], dgs[S2_NPW], cidx[S2_NPW];
#pragma unroll
    for (int n = 0; n < S2_NPW; ++n) {
        rs[n] = row_start[base_node + n];
        dgs[n] = deg[base_node + n];
    }
#pragma unroll
    for (int n = 0; n < S2_NPW; ++n)
        cidx[n] = (lane < dgs[n]) ? col[rs[n] + lane] : 0;

    // hoist ALL nodes' first-iteration loads (node-boundary overlap).
    // masked loads: group-uniform exec mask suppresses round-up transactions;
    // fp8 0x00 decodes to 0.0 so consumption needs no predicate.
    unsigned pv0[S2_NPW], pv1[S2_NPW];
#pragma unroll
    for (int n = 0; n < S2_NPW; ++n) {
        int dgc = (dgs[n] < 64) ? dgs[n] : 64;
        int i0 = __shfl(cidx[n], g, 64);
        int i1 = __shfl(cidx[n], 4 + g, 64);
        pv0[n] = 0; pv1[n] = 0;
        if (g < dgc)     pv0[n] = *(const unsigned*)(p + i0 * 64 + c * 4);
        if (4 + g < dgc) pv1[n] = *(const unsigned*)(p + i1 * 64 + c * 4);
    }

    for (int n = 0; n < S2_NPW; ++n) {
        int node = base_node + n;
        int dg = dgs[n];
        int dgc = (dg < 64) ? dg : 64;

        float4 a0 = {0.f,0.f,0.f,0.f}, a1 = {0.f,0.f,0.f,0.f};
        unsigned v0 = pv0[n], v1 = pv1[n];
        for (int j = 0; j < dgc; j += 8) {
            // prefetch iteration j+8 (shfl outside the branch: all lanes active)
            int nj0 = j + 8 + g, nj1 = j + 12 + g;
            int k0 = __shfl(cidx[n], nj0 & 63, 64);
            int k1 = __shfl(cidx[n], nj1 & 63, 64);
            unsigned w0 = 0, w1 = 0;
            if (nj0 < dgc) w0 = *(const unsigned*)(p + k0 * 64 + c * 4);
            if (nj1 < dgc) w1 = *(const unsigned*)(p + k1 * 64 + c * 4);
            // consume current (masked-off slots hold 0 -> adds 0)
            a0.x += __builtin_amdgcn_cvt_f32_fp8(v0, 0);
            a0.y += __builtin_amdgcn_cvt_f32_fp8(v0, 1);
            a0.z += __builtin_amdgcn_cvt_f32_fp8(v0, 2);
            a0.w += __builtin_amdgcn_cvt_f32_fp8(v0, 3);
            a1.x += __builtin_amdgcn_cvt_f32_fp8(v1, 0);
            a1.y += __builtin_amdgcn_cvt_f32_fp8(v1, 1);
            a1.z += __builtin_amdgcn_cvt_f32_fp8(v1, 2);
            a1.w += __builtin_amdgcn_cvt_f32_fp8(v1, 3);
            v0 = w0; v1 = w1;
        }
        for (int k = 64; k < dg; ++k) {                 // deg>64 tail (rare)
            int r = col[rs[n] + k];
            unsigned v = *(const unsigned*)(p + r * 64 + c * 4);
            if (g == 0) {
                a0.x += __builtin_amdgcn_cvt_f32_fp8(v, 0);
                a0.y += __builtin_amdgcn_cvt_f32_fp8(v, 1);
                a0.z += __builtin_amdgcn_cvt_f32_fp8(v, 2);
                a0.w += __builtin_amdgcn_cvt_f32_fp8(v, 3);
            }
        }
        float sx = a0.x + a1.x, sy = a0.y + a1.y, sz = a0.z + a1.z, sw = a0.w + a1.w;
        // combine across the 4 row-groups (lanes {L, L^16, L^32, L^48})
        sx += __shfl_xor(sx, 16, 64); sx += __shfl_xor(sx, 32, 64);
        sy += __shfl_xor(sy, 16, 64); sy += __shfl_xor(sy, 32, 64);
        sz += __shfl_xor(sz, 16, 64); sz += __shfl_xor(sz, 32, 64);
        sw += __shfl_xor(sw, 16, 64); sw += __shfl_xor(sw, 32, 64);

        float inv = 1.0f / fmaxf((float)dg, 1.0f);
        ushort4 qv = *(const ushort4*)(q + node * 64 + c * 4);
        float h0 = fmaxf(sx * inv + b2v.x + bf2f(qv.x), 0.f);
        float h1 = fmaxf(sy * inv + b2v.y + bf2f(qv.y), 0.f);
        float h2 = fmaxf(sz * inv + b2v.z + bf2f(qv.z), 0.f);
        float h3 = fmaxf(sw * inv + b2v.w + bf2f(qv.w), 0.f);

        float p0 = h0 * w01.x + h1 * w01.z + h2 * w23.x + h3 * w23.z;
        float p1 = h0 * w01.y + h1 * w01.w + h2 * w23.y + h3 * w23.w;
        if (g != 0) { p0 = 0.f; p1 = 0.f; }             // groups duplicate
        p0 += __shfl_down(p0, 8, 64);  p1 += __shfl_down(p1, 8, 64);
        p0 += __shfl_down(p0, 4, 64);  p1 += __shfl_down(p1, 4, 64);
        p0 += __shfl_down(p0, 2, 64);  p1 += __shfl_down(p1, 2, 64);
        p0 += __shfl_down(p0, 1, 64);  p1 += __shfl_down(p1, 1, 64);
        if (lane == 0) {
            int grp = batch[node];
            atomicAdd(&gsum[grp * 2 + 0], p0);
            atomicAdd(&gsum[grp * 2 + 1], p1);
        }
    }
}

// ---------------- finalize: out = gsum/cnt + bout ----------------
__global__ __launch_bounds__(256) void finalize_kernel(
    const float* __restrict__ gsum, const int* __restrict__ gstart,
    const float* __restrict__ bout, float* __restrict__ out)
{
    int g = blockIdx.x * 256 + threadIdx.x;
    if (g >= N_GRAPHS) return;
    int cnt = gstart[g + 1] - gstart[g];
    float inv = 1.0f / fmaxf((float)cnt, 1.0f);
    out[g * 2 + 0] = gsum[g * 2 + 0] * inv + bout[0];
    out[g * 2 + 1] = gsum[g * 2 + 1] * inv + bout[1];
}

extern "C" void kernel_launch(void* const* d_in, const int* in_sizes, int n_in,
                              void* d_out, int out_size, void* d_ws, size_t ws_size,
                              hipStream_t stream) {
    const int*   x    = (const int*)  d_in[0];
    const int*   ei   = (const int*)  d_in[1];
    const int*   batch= (const int*)  d_in[2];
    const float* emb  = (const float*)d_in[3];
    const float* W1l  = (const float*)d_in[4];
    const float* b1   = (const float*)d_in[5];
    const float* W1r  = (const float*)d_in[6];
    const float* W2l  = (const float*)d_in[7];
    const float* b2   = (const float*)d_in[8];
    const float* W2r  = (const float*)d_in[9];
    const float* Wout = (const float*)d_in[10];
    const float* bout = (const float*)d_in[11];
    float* out = (float*)d_out;

    const int* src = ei;
    const int* dst = ei + N_EDGES;

    char* ws = (char*)d_ws;
    size_t off = 0;
    unsigned char*  p8     = (unsigned char*) (ws + off); off += (size_t)N_NODES * 64;      // 6.4 MB
    unsigned short* q16    = (unsigned short*)(ws + off); off += (size_t)N_NODES * 64 * 2;  // 12.8 MB
    unsigned short* h1b    = (unsigned short*)(ws + off); off += (size_t)N_NODES * 64 * 2;  // 12.8 MB
    unsigned short* w2frag = (unsigned short*)(ws + off); off += (size_t)8192 * 2;
    float*    embW1l = (float*)   (ws + off); off += (size_t)VOCAB * 64 * 4;
    float*    embW1r = (float*)   (ws + off); off += (size_t)VOCAB * 64 * 4;
    int*      rowst  = (int*)     (ws + off); off += (size_t)N_NODES * 4;
    int*      deg    = (int*)     (ws + off); off += (size_t)N_NODES * 4;
    int*      col    = (int*)     (ws + off); off += (size_t)(NBK * CAP + 256) * 4;
    unsigned* edge8  = (unsigned*)(ws + off); off += (size_t)NBK * CAP * 4;
    int*      cursor = (int*)     (ws + off); off += (size_t)NBK * 4;
    int*      gstart = (int*)     (ws + off); off += (size_t)(N_GRAPHS + 1) * 4;
    float*    gsum   = (float*)   (ws + off); off += (size_t)N_GRAPHS * 2 * 4;

    setup_kernel<<<GB + 32 + 1, 256, 0, stream>>>(
        batch, gstart, emb, W1l, W1r, W2l, W2r, embW1l, embW1r, w2frag,
        cursor, gsum);
    scatter_kernel<<<SCAT_BLOCKS, 256, 0, stream>>>(src, dst, cursor, edge8);
    csr_kernel<<<NBK, 256, 0, stream>>>(edge8, cursor, rowst, deg, col);
    sage1_kernel<<<N_NODES / (4 * S1_NPW), 256, 0, stream>>>(
        x, embW1l, embW1r, b1, rowst, deg, col, h1b);
    mfma_transform_kernel<<<(N_NODES + 63) / 64, 256, 0, stream>>>(
        h1b, w2frag, p8, q16);
    sage2_kernel<<<N_NODES / (4 * S2_NPW), 256, 0, stream>>>(
        p8, q16, rowst, deg, col, b2, Wout, batch, gsum);
    finalize_kernel<<<(N_GRAPHS + 255) / 256, 256, 0, stream>>>(gsum, gstart, bout, out);
}

// Round 13
// 228.722 us; speedup vs baseline: 1.1457x; 1.1457x over previous
//
#include <hip/hip_runtime.h>
#include <hip/hip_bf16.h>

#define N_NODES 100000
#define N_EDGES 1000000
#define EMB 64
#define HID 64
#define VOCAB 128
#define N_GRAPHS 2048

#define CBUCKET 1024                                   // nodes per bucket
#define NBK ((N_NODES + CBUCKET - 1) / CBUCKET)        // 98
#define CAP 16384                                      // slots per bucket (E[cnt]=10204)
#define CHUNK 4096
#define SCAT_BLOCKS ((N_EDGES + CHUNK - 1) / CHUNK)    // 245
#define GB ((N_NODES + 255) / 256)                     // 391 gstart blocks

#define BCASTF(v, l) __int_as_float(__builtin_amdgcn_readlane(__float_as_int(v), (l)))

typedef __attribute__((ext_vector_type(8))) short short8;
typedef __attribute__((ext_vector_type(4))) float f32x4;

__device__ __forceinline__ float bf2f(unsigned short u) {
    return __uint_as_float((unsigned)u << 16);
}
__device__ __forceinline__ unsigned short f2bf(float f) {
    return __bfloat16_as_ushort(__float2bfloat16(f));
}

// ---- fused setup: gstart (blocks 0..GB-1) + precompute (GB..GB+31) + init --
__global__ __launch_bounds__(256) void setup_kernel(
    const int* __restrict__ batch, int* __restrict__ gstart,
    const float* __restrict__ emb, const float* __restrict__ W1l,
    const float* __restrict__ W1r,
    const float* __restrict__ W2l, const float* __restrict__ W2r,
    float* __restrict__ embW1l, float* __restrict__ embW1r,
    unsigned short* __restrict__ w2frag,
    int* __restrict__ cursor, float* __restrict__ gsum)
{
    int b = blockIdx.x;
    int t = threadIdx.x;
    if (b < GB) {
        // graph boundaries (batch sorted)
        int i = b * 256 + t;
        if (i >= N_NODES) return;
        int bg = batch[i];
        int bp = (i == 0) ? -1 : batch[i - 1];
        for (int g = bp + 1; g <= bg; ++g) gstart[g] = i;
        if (i == N_NODES - 1)
            for (int g = bg + 1; g <= N_GRAPHS; ++g) gstart[g] = N_NODES;
    } else if (b < GB + 32) {
        int vb = b - GB;
        int wave = t >> 6, lane = t & 63;
        int v = vb * 4 + wave;
        if (v < VOCAB) {
            float er = emb[v * 64 + lane];       // lane = d
            float al = 0.f, ar = 0.f;
#pragma unroll 8
            for (int d = 0; d < 64; ++d) {
                float e = BCASTF(er, d);
                al += e * W1l[d * 64 + lane];
                ar += e * W1r[d * 64 + lane];
            }
            embW1l[v * 64 + lane] = al;
            embW1r[v * 64 + lane] = ar;
        }
        // W2 B-fragment packing: g = tt*1024 + h*512 + l*8 + j
        int g = vb * 256 + t;
        int j = g & 7, l = (g >> 3) & 63, h = (g >> 9) & 1, tt = g >> 10;
        int k = h * 32 + ((l >> 4) * 8) + j;
        int n = tt * 16 + (l & 15);
        float w = (n < 64) ? W2l[k * 64 + n] : W2r[k * 64 + (n - 64)];
        w2frag[g] = f2bf(w);
    } else {
        if (t < NBK) cursor[t] = t * CAP;
        for (int i = t; i < N_GRAPHS * 2; i += 256) gsum[i] = 0.f;
    }
}

// ---- scatter: LDS-staged chunk, per-(block,bucket) run reservation ----
// payload now 64-bit: src (17b) | x[src] (7b, bits 17..23) | local_dst (10b, bits 24..33)
__global__ __launch_bounds__(256) void scatter_kernel(
    const int* __restrict__ src, const int* __restrict__ dst,
    const int* __restrict__ x,
    int* __restrict__ cursor, unsigned long long* __restrict__ edge8)
{
    __shared__ unsigned long long earr[CHUNK];  // 32 KB packed payload
    __shared__ unsigned char karr[CHUNK];       // 4 KB bucket key
    __shared__ int bcnt[NBK];
    __shared__ int bbase[NBK];
    int t = threadIdx.x;
    if (t < NBK) bcnt[t] = 0;
    __syncthreads();
    int e0 = blockIdx.x * CHUNK;
    int n = min(e0 + CHUNK, N_EDGES) - e0;
    for (int i = t; i < n; i += 256) {
        int d = dst[e0 + i];
        int s = src[e0 + i];
        int xv = x[s];                          // random 4B read, 400KB L2-hot
        int k = d >> 10;
        earr[i] = (unsigned long long)s
                | ((unsigned long long)xv << 17)
                | ((unsigned long long)(d & 1023) << 24);
        karr[i] = (unsigned char)k;
        atomicAdd(&bcnt[k], 1);
    }
    __syncthreads();
    if (t < NBK) {
        int c = bcnt[t];
        bbase[t] = c ? atomicAdd(&cursor[t], c) : 0;
        bcnt[t] = 0;                        // reuse as local cursor
    }
    __syncthreads();
    for (int i = t; i < n; i += 256) {
        int k = karr[i];
        int off = atomicAdd(&bcnt[k], 1);
        edge8[bbase[k] + off] = earr[i];    // dense single-writer runs
    }
}

// ---- per-bucket CSR build (rowstart/deg/col), dense writes ------
// col entry = src (17b) | x[src] (7b) -> sage1 needs no x gather at all
__global__ __launch_bounds__(256) void csr_kernel(
    const unsigned long long* __restrict__ edge8, const int* __restrict__ cursor,
    int* __restrict__ row_start, int* __restrict__ deg, int* __restrict__ col)
{
    __shared__ int cnt[CBUCKET];
    __shared__ int ssum[256];
    int b = blockIdx.x;                   // NBK blocks
    int t = threadIdx.x;
    int lo = b * CAP, hi = cursor[b];     // cursor holds final fill level
    for (int i = t; i < CBUCKET; i += 256) cnt[i] = 0;
    __syncthreads();
    for (int i = lo + t; i < hi; i += 256)
        atomicAdd(&cnt[(int)(edge8[i] >> 24)], 1);
    __syncthreads();
    int v[4]; int sum = 0;
#pragma unroll
    for (int i = 0; i < 4; ++i) { v[i] = cnt[t * 4 + i]; sum += v[i]; }
    ssum[t] = sum;
    __syncthreads();
    for (int off = 1; off < 256; off <<= 1) {
        int tmp = (t >= off) ? ssum[t - off] : 0;
        __syncthreads();
        ssum[t] += tmp;
        __syncthreads();
    }
    int run = ssum[t] - sum;
    int ex0 = run, ex1 = ex0 + v[0], ex2 = ex1 + v[1], ex3 = ex2 + v[2];
    int node = b * CBUCKET + t * 4;
    if (node + 3 < N_NODES) {
        *(int4*)&row_start[node] = make_int4(lo + ex0, lo + ex1, lo + ex2, lo + ex3);
        *(int4*)&deg[node]       = make_int4(v[0], v[1], v[2], v[3]);
    } else {
        int ex[4] = {ex0, ex1, ex2, ex3};
        for (int i = 0; i < 4; ++i)
            if (node + i < N_NODES) { row_start[node + i] = lo + ex[i]; deg[node + i] = v[i]; }
    }
    cnt[t * 4 + 0] = ex0; cnt[t * 4 + 1] = ex1;       // reuse as cursors
    cnt[t * 4 + 2] = ex2; cnt[t * 4 + 3] = ex3;
    __syncthreads();
    for (int i = lo + t; i < hi; i += 256) {
        unsigned long long e = edge8[i];
        int slot = atomicAdd(&cnt[(int)(e >> 24)], 1);
        col[lo + slot] = (int)(e & 0xFFFFFF);         // src | x<<17 (24 bits)
    }
}

// ---- layer 1: h1 = relu(mean_j(embW1l[x_j]) + b1 + embW1r[x_i]) ----
// neighbor vocab ids come packed in col (bits 17..23): NO random x gather.
#define S1_NPW 8
__global__ __launch_bounds__(256) void sage1_kernel(
    const int* __restrict__ x, const float* __restrict__ embW1l,
    const float* __restrict__ embW1r, const float* __restrict__ b1,
    const int* __restrict__ row_start, const int* __restrict__ deg,
    const int* __restrict__ col, unsigned short* __restrict__ h1b)
{
    __shared__ float elds[VOCAB * 64];      // 32 KB -> 5 blocks/CU
    int t = threadIdx.x;
    for (int i = t * 4; i < VOCAB * 64; i += 1024)
        *(float4*)&elds[i] = *(const float4*)&embW1l[i];
    __syncthreads();

    int wave = t >> 6, lane = t & 63;
    int base_node = (blockIdx.x * 4 + wave) * S1_NPW;   // 3125*32 = 100000 exact
    float bias = b1[lane];

    int rs[S1_NPW], dgs[S1_NPW], cidx[S1_NPW], xn[S1_NPW];
    float self[S1_NPW];
#pragma unroll
    for (int n = 0; n < S1_NPW; ++n) {
        rs[n] = row_start[base_node + n];
        dgs[n] = deg[base_node + n];
        xn[n] = x[base_node + n];
    }
#pragma unroll
    for (int n = 0; n < S1_NPW; ++n) {
        cidx[n] = (lane < dgs[n]) ? col[rs[n] + lane] : 0;
        self[n] = embW1r[xn[n] * 64 + lane];
    }

    for (int n = 0; n < S1_NPW; ++n) {
        int node = base_node + n;
        int dg = dgs[n];
        int dgc = (dg < 64) ? dg : 64;

        float s0 = 0.f, s1 = 0.f, s2 = 0.f, s3 = 0.f;
        int j = 0;
        for (; j + 4 <= dgc; j += 4) {
            int x0 = __builtin_amdgcn_readlane(cidx[n], j + 0) >> 17;
            int x1 = __builtin_amdgcn_readlane(cidx[n], j + 1) >> 17;
            int x2 = __builtin_amdgcn_readlane(cidx[n], j + 2) >> 17;
            int x3 = __builtin_amdgcn_readlane(cidx[n], j + 3) >> 17;
            s0 += elds[x0 * 64 + lane];
            s1 += elds[x1 * 64 + lane];
            s2 += elds[x2 * 64 + lane];
            s3 += elds[x3 * 64 + lane];
        }
        for (; j < dgc; ++j) {
            int x0 = __builtin_amdgcn_readlane(cidx[n], j) >> 17;
            s0 += elds[x0 * 64 + lane];
        }
        for (int k = 64; k < dg; ++k) {                 // deg>64 tail (rare)
            int c = col[rs[n] + k];
            s0 += elds[(c >> 17) * 64 + lane];
        }
        float mean = ((s0 + s1) + (s2 + s3)) / fmaxf((float)dg, 1.0f);
        h1b[node * 64 + lane] = f2bf(fmaxf(mean + bias + self[n], 0.f));
    }
}

// ---- MFMA transform: [p|q] = h1 @ [W2l|W2r]  (M=100000, N=128, K=64) ----
// p stored fp8 e4m3 (gathered later -> smaller working set), q stored bf16.
__global__ __launch_bounds__(256) void mfma_transform_kernel(
    const unsigned short* __restrict__ h1b,
    const unsigned short* __restrict__ w2frag,
    unsigned char* __restrict__ p8, unsigned short* __restrict__ q16)
{
    int wave = threadIdx.x >> 6, lane = threadIdx.x & 63;
    int base16 = blockIdx.x * 64 + wave * 16;
    if (base16 >= N_NODES) return;                      // tail waves only
    int m = lane & 15, quad = lane >> 4;

    const unsigned short* arow = h1b + (base16 + m) * 64 + quad * 8;
    short8 a0 = *(const short8*)(arow);                 // k = 0..31
    short8 a1 = *(const short8*)(arow + 32);            // k = 32..63

#pragma unroll
    for (int tt = 0; tt < 8; ++tt) {                    // 8 output tiles of 16
        short8 b0 = *(const short8*)(w2frag + (tt * 1024 + 0)   + lane * 8);
        short8 b1 = *(const short8*)(w2frag + (tt * 1024 + 512) + lane * 8);
        f32x4 acc = {0.f, 0.f, 0.f, 0.f};
        acc = __builtin_amdgcn_mfma_f32_16x16x32_bf16(a0, b0, acc, 0, 0, 0);
        acc = __builtin_amdgcn_mfma_f32_16x16x32_bf16(a1, b1, acc, 0, 0, 0);
        int o = tt * 16 + m;
        if (o < 64) {
            // p: pack to fp8 e4m3 (rows i, i+1 share a pk convert)
            int pk01 = __builtin_amdgcn_cvt_pk_fp8_f32(acc[0], acc[1], 0, false);
            int pk23 = __builtin_amdgcn_cvt_pk_fp8_f32(acc[2], acc[3], 0, false);
            p8[(base16 + quad * 4 + 0) * 64 + o] = (unsigned char)(pk01 & 0xff);
            p8[(base16 + quad * 4 + 1) * 64 + o] = (unsigned char)((pk01 >> 8) & 0xff);
            p8[(base16 + quad * 4 + 2) * 64 + o] = (unsigned char)(pk23 & 0xff);
            p8[(base16 + quad * 4 + 3) * 64 + o] = (unsigned char)((pk23 >> 8) & 0xff);
        } else {
            int oc = o & 63;
#pragma unroll
            for (int i = 0; i < 4; ++i) {
                int node = base16 + quad * 4 + i;
                q16[node * 64 + oc] = f2bf(acc[i]);
            }
        }
    }
}

// ---- gather (r11-proven structure, fp8 rows): 4 features/lane, uint load --
//   h2 = relu(mean_j p_j + b2 + q_i);  gsum[batch] += h2 @ Wout
#define S2_NPW 8
__global__ __launch_bounds__(256, 6) void sage2_kernel(
    const unsigned char* __restrict__ p, const unsigned short* __restrict__ q,
    const int* __restrict__ row_start, const int* __restrict__ deg,
    const int* __restrict__ col, const float* __restrict__ b2,
    const float* __restrict__ Wout, const int* __restrict__ batch,
    float* __restrict__ gsum)
{
    int t = threadIdx.x;
    int wave = t >> 6, lane = t & 63;
    int base_node = (blockIdx.x * 4 + wave) * S2_NPW;   // exact cover
    int c = lane & 15;          // feature quad: features 4c..4c+3
    int g = lane >> 4;          // row group 0..3

    float4 b2v = ((const float4*)b2)[c];
    float4 w01 = ((const float4*)Wout)[c * 2];
    float4 w23 = ((const float4*)Wout)[c * 2 + 1];

    // prefetch per-node metadata + neighbor index rows for all 8 nodes
    int rs[S2_NPW], dgs[S2_NPW], cidx[S2_NPW];
#pragma unroll
    for (int n = 0; n < S2_NPW; ++n) {
        rs[n] = row_start[base_node + n];
        dgs[n] = deg[base_node + n];
    }
#pragma unroll
    for (int n = 0; n < S2_NPW; ++n)
        cidx[n] = (lane < dgs[n]) ? (col[rs[n] + lane] & 0x1FFFF) : 0;

    for (int n = 0; n < S2_NPW; ++n) {
        int node = base_node + n;
        int dg = dgs[n];
        int dgc = (dg < 64) ? dg : 64;

        // each iteration: 2 loads x 4 rows = 8 rows in flight (256 B each)
        float4 a0 = {0.f,0.f,0.f,0.f}, a1 = {0.f,0.f,0.f,0.f};
        for (int j = 0; j < dgc; j += 8) {
            int jj0 = j + g, jj1 = j + 4 + g;           // < 64 always
            int i0 = __shfl(cidx[n], jj0, 64);
            int i1 = __shfl(cidx[n], jj1, 64);
            unsigned v0 = *(const unsigned*)(p + i0 * 64 + c * 4);
            unsigned v1 = *(const unsigned*)(p + i1 * 64 + c * 4);
            if (jj0 < dgc) {
                a0.x += __builtin_amdgcn_cvt_f32_fp8(v0, 0);
                a0.y += __builtin_amdgcn_cvt_f32_fp8(v0, 1);
                a0.z += __builtin_amdgcn_cvt_f32_fp8(v0, 2);
                a0.w += __builtin_amdgcn_cvt_f32_fp8(v0, 3);
            }
            if (jj1 < dgc) {
                a1.x += __builtin_amdgcn_cvt_f32_fp8(v1, 0);
                a1.y += __builtin_amdgcn_cvt_f32_fp8(v1, 1);
                a1.z += __builtin_amdgcn_cvt_f32_fp8(v1, 2);
                a1.w += __builtin_amdgcn_cvt_f32_fp8(v1, 3);
            }
        }
        for (int k = 64; k < dg; ++k) {                 // deg>64 tail (rare)
            int r = col[rs[n] + k] & 0x1FFFF;
            unsigned v = *(const unsigned*)(p + r * 64 + c * 4);
            if (g == 0) {
                a0.x += __builtin_amdgcn_cvt_f32_fp8(v, 0);
                a0.y += __builtin_amdgcn_cvt_f32_fp8(v, 1);
                a0.z += __builtin_amdgcn_cvt_f32_fp8(v, 2);
                a0.w += __builtin_amdgcn_cvt_f32_fp8(v, 3);
            }
        }
        float sx = a0.x + a1.x, sy = a0.y + a1.y, sz = a0.z + a1.z, sw = a0.w + a1.w;
        // combine across the 4 row-groups (lanes {L, L^16, L^32, L^48})
        sx += __shfl_xor(sx, 16, 64); sx += __shfl_xor(sx, 32, 64);
        sy += __shfl_xor(sy, 16, 64); sy += __shfl_xor(sy, 32, 64);
        sz += __shfl_xor(sz, 16, 64); sz += __shfl_xor(sz, 32, 64);
        sw += __shfl_xor(sw, 16, 64); sw += __shfl_xor(sw, 32, 64);

        float inv = 1.0f / fmaxf((float)dg, 1.0f);
        ushort4 qv = *(const ushort4*)(q + node * 64 + c * 4);
        float h0 = fmaxf(sx * inv + b2v.x + bf2f(qv.x), 0.f);
        float h1 = fmaxf(sy * inv + b2v.y + bf2f(qv.y), 0.f);
        float h2 = fmaxf(sz * inv + b2v.z + bf2f(qv.z), 0.f);
        float h3 = fmaxf(sw * inv + b2v.w + bf2f(qv.w), 0.f);

        float p0 = h0 * w01.x + h1 * w01.z + h2 * w23.x + h3 * w23.z;
        float p1 = h0 * w01.y + h1 * w01.w + h2 * w23.y + h3 * w23.w;
        if (g != 0) { p0 = 0.f; p1 = 0.f; }             // groups duplicate
        p0 += __shfl_down(p0, 8, 64);  p1 += __shfl_down(p1, 8, 64);
        p0 += __shfl_down(p0, 4, 64);  p1 += __shfl_down(p1, 4, 64);
        p0 += __shfl_down(p0, 2, 64);  p1 += __shfl_down(p1, 2, 64);
        p0 += __shfl_down(p0, 1, 64);  p1 += __shfl_down(p1, 1, 64);
        if (lane == 0) {
            int grp = batch[node];
            atomicAdd(&gsum[grp * 2 + 0], p0);
            atomicAdd(&gsum[grp * 2 + 1], p1);
        }
    }
}

// ---------------- finalize: out = gsum/cnt + bout ----------------
__global__ __launch_bounds__(256) void finalize_kernel(
    const float* __restrict__ gsum, const int* __restrict__ gstart,
    const float* __restrict__ bout, float* __restrict__ out)
{
    int g = blockIdx.x * 256 + threadIdx.x;
    if (g >= N_GRAPHS) return;
    int cnt = gstart[g + 1] - gstart[g];
    float inv = 1.0f / fmaxf((float)cnt, 1.0f);
    out[g * 2 + 0] = gsum[g * 2 + 0] * inv + bout[0];
    out[g * 2 + 1] = gsum[g * 2 + 1] * inv + bout[1];
}

extern "C" void kernel_launch(void* const* d_in, const int* in_sizes, int n_in,
                              void* d_out, int out_size, void* d_ws, size_t ws_size,
                              hipStream_t stream) {
    const int*   x    = (const int*)  d_in[0];
    const int*   ei   = (const int*)  d_in[1];
    const int*   batch= (const int*)  d_in[2];
    const float* emb  = (const float*)d_in[3];
    const float* W1l  = (const float*)d_in[4];
    const float* b1   = (const float*)d_in[5];
    const float* W1r  = (const float*)d_in[6];
    const float* W2l  = (const float*)d_in[7];
    const float* b2   = (const float*)d_in[8];
    const float* W2r  = (const float*)d_in[9];
    const float* Wout = (const float*)d_in[10];
    const float* bout = (const float*)d_in[11];
    float* out = (float*)d_out;

    const int* src = ei;
    const int* dst = ei + N_EDGES;

    char* ws = (char*)d_ws;
    size_t off = 0;
    unsigned char*  p8     = (unsigned char*) (ws + off); off += (size_t)N_NODES * 64;      // 6.4 MB
    unsigned short* q16    = (unsigned short*)(ws + off); off += (size_t)N_NODES * 64 * 2;  // 12.8 MB
    unsigned short* h1b    = (unsigned short*)(ws + off); off += (size_t)N_NODES * 64 * 2;  // 12.8 MB
    unsigned short* w2frag = (unsigned short*)(ws + off); off += (size_t)8192 * 2;
    float*    embW1l = (float*)   (ws + off); off += (size_t)VOCAB * 64 * 4;
    float*    embW1r = (float*)   (ws + off); off += (size_t)VOCAB * 64 * 4;
    int*      rowst  = (int*)     (ws + off); off += (size_t)N_NODES * 4;
    int*      deg    = (int*)     (ws + off); off += (size_t)N_NODES * 4;
    int*      col    = (int*)     (ws + off); off += (size_t)(NBK * CAP + 256) * 4;
    off = (off + 7) & ~(size_t)7;                       // 8B align for edge8
    unsigned long long* edge8 = (unsigned long long*)(ws + off);
    off += (size_t)NBK * CAP * 8;                       // 12.8 MB
    int*      cursor = (int*)     (ws + off); off += (size_t)NBK * 4;
    int*      gstart = (int*)     (ws + off); off += (size_t)(N_GRAPHS + 1) * 4;
    float*    gsum   = (float*)   (ws + off); off += (size_t)N_GRAPHS * 2 * 4;

    setup_kernel<<<GB + 32 + 1, 256, 0, stream>>>(
        batch, gstart, emb, W1l, W1r, W2l, W2r, embW1l, embW1r, w2frag,
        cursor, gsum);
    scatter_kernel<<<SCAT_BLOCKS, 256, 0, stream>>>(src, dst, x, cursor, edge8);
    csr_kernel<<<NBK, 256, 0, stream>>>(edge8, cursor, rowst, deg, col);
    sage1_kernel<<<N_NODES / (4 * S1_NPW), 256, 0, stream>>>(
        x, embW1l, embW1r, b1, rowst, deg, col, h1b);
    mfma_transform_kernel<<<(N_NODES + 63) / 64, 256, 0, stream>>>(
        h1b, w2frag, p8, q16);
    sage2_kernel<<<N_NODES / (4 * S2_NPW), 256, 0, stream>>>(
        p8, q16, rowst, deg, col, b2, Wout, batch, gsum);
    finalize_kernel<<<(N_GRAPHS + 255) / 256, 256, 0, stream>>>(gsum, gstart, bout, out);
}

// Round 14
// 217.753 us; speedup vs baseline: 1.2034x; 1.0504x over previous
//
#include <hip/hip_runtime.h>
#include <hip/hip_bf16.h>

#define N_NODES 100000
#define N_EDGES 1000000
#define EMB 64
#define HID 64
#define VOCAB 128
#define N_GRAPHS 2048

#define CBUCKET 256                                    // nodes per bucket
#define NBK ((N_NODES + CBUCKET - 1) / CBUCKET)        // 391
#define CAP 4096                                       // slots per bucket (E[cnt]=2560)
#define CHUNK 4096
#define SCAT_BLOCKS ((N_EDGES + CHUNK - 1) / CHUNK)    // 245
#define GB ((N_NODES + 255) / 256)                     // 391 gstart blocks

#define BCASTF(v, l) __int_as_float(__builtin_amdgcn_readlane(__float_as_int(v), (l)))

typedef __attribute__((ext_vector_type(8))) short short8;
typedef __attribute__((ext_vector_type(4))) float f32x4;

__device__ __forceinline__ float bf2f(unsigned short u) {
    return __uint_as_float((unsigned)u << 16);
}
__device__ __forceinline__ unsigned short f2bf(float f) {
    return __bfloat16_as_ushort(__float2bfloat16(f));
}

// ---- fused setup: gstart (blocks 0..GB-1) + precompute (GB..GB+31) + init --
__global__ __launch_bounds__(256) void setup_kernel(
    const int* __restrict__ batch, int* __restrict__ gstart,
    const float* __restrict__ emb, const float* __restrict__ W1l,
    const float* __restrict__ W1r,
    const float* __restrict__ W2l, const float* __restrict__ W2r,
    float* __restrict__ embW1l, float* __restrict__ embW1r,
    unsigned short* __restrict__ w2frag,
    int* __restrict__ cursor, float* __restrict__ gsum)
{
    int b = blockIdx.x;
    int t = threadIdx.x;
    if (b < GB) {
        // graph boundaries (batch sorted)
        int i = b * 256 + t;
        if (i >= N_NODES) return;
        int bg = batch[i];
        int bp = (i == 0) ? -1 : batch[i - 1];
        for (int g = bp + 1; g <= bg; ++g) gstart[g] = i;
        if (i == N_NODES - 1)
            for (int g = bg + 1; g <= N_GRAPHS; ++g) gstart[g] = N_NODES;
    } else if (b < GB + 32) {
        int vb = b - GB;
        int wave = t >> 6, lane = t & 63;
        int v = vb * 4 + wave;
        if (v < VOCAB) {
            float er = emb[v * 64 + lane];       // lane = d
            float al = 0.f, ar = 0.f;
#pragma unroll 8
            for (int d = 0; d < 64; ++d) {
                float e = BCASTF(er, d);
                al += e * W1l[d * 64 + lane];
                ar += e * W1r[d * 64 + lane];
            }
            embW1l[v * 64 + lane] = al;
            embW1r[v * 64 + lane] = ar;
        }
        // W2 B-fragment packing: g = tt*1024 + h*512 + l*8 + j
        int g = vb * 256 + t;
        int j = g & 7, l = (g >> 3) & 63, h = (g >> 9) & 1, tt = g >> 10;
        int k = h * 32 + ((l >> 4) * 8) + j;
        int n = tt * 16 + (l & 15);
        float w = (n < 64) ? W2l[k * 64 + n] : W2r[k * 64 + (n - 64)];
        w2frag[g] = f2bf(w);
    } else {
        for (int i = t; i < NBK; i += 256) cursor[i] = i * CAP;
        for (int i = t; i < N_GRAPHS * 2; i += 256) gsum[i] = 0.f;
    }
}

// ---- scatter: LDS-staged chunk, per-(block,bucket) run reservation ----
// 32-bit payload: src (17b) | x[src] (7b, bits 17..23) | local_dst (8b, bits 24..31)
__global__ __launch_bounds__(256) void scatter_kernel(
    const int* __restrict__ src, const int* __restrict__ dst,
    const int* __restrict__ x,
    int* __restrict__ cursor, unsigned* __restrict__ edge8)
{
    __shared__ unsigned earr[CHUNK];            // 16 KB packed payload
    __shared__ unsigned short karr[CHUNK];      // 8 KB bucket key (0..390)
    __shared__ int bcnt[NBK];
    __shared__ int bbase[NBK];
    int t = threadIdx.x;
    for (int i = t; i < NBK; i += 256) bcnt[i] = 0;
    __syncthreads();
    int e0 = blockIdx.x * CHUNK;
    int n = min(e0 + CHUNK, N_EDGES) - e0;
    for (int i = t; i < n; i += 256) {
        int d = dst[e0 + i];
        int s = src[e0 + i];
        int xv = x[s];                          // random 4B read, 400KB L2-hot
        int k = d >> 8;
        earr[i] = (unsigned)s | ((unsigned)xv << 17) | ((unsigned)(d & 255) << 24);
        karr[i] = (unsigned short)k;
        atomicAdd(&bcnt[k], 1);
    }
    __syncthreads();
    for (int i = t; i < NBK; i += 256) {
        int c = bcnt[i];
        bbase[i] = c ? atomicAdd(&cursor[i], c) : 0;
        bcnt[i] = 0;                            // reuse as local cursor
    }
    __syncthreads();
    for (int i = t; i < n; i += 256) {
        int k = karr[i];
        int off = atomicAdd(&bcnt[k], 1);
        edge8[bbase[k] + off] = earr[i];        // dense single-writer runs
    }
}

// ---- per-bucket CSR build (rowstart/deg/col), dense writes ------
// col entry = src (17b) | x[src] (7b) -> sage1 needs no x gather at all
__global__ __launch_bounds__(256) void csr_kernel(
    const unsigned* __restrict__ edge8, const int* __restrict__ cursor,
    int* __restrict__ row_start, int* __restrict__ deg, int* __restrict__ col)
{
    __shared__ int cnt[CBUCKET];
    __shared__ int scn[CBUCKET];
    int b = blockIdx.x;                   // NBK blocks
    int t = threadIdx.x;
    int lo = b * CAP, hi = cursor[b];     // cursor holds final fill level
    cnt[t] = 0;
    __syncthreads();
    for (int i = lo + t; i < hi; i += 256)
        atomicAdd(&cnt[edge8[i] >> 24], 1);
    __syncthreads();
    int v = cnt[t];
    scn[t] = v;
    __syncthreads();
    for (int off = 1; off < 256; off <<= 1) {
        int tmp = (t >= off) ? scn[t - off] : 0;
        __syncthreads();
        scn[t] += tmp;
        __syncthreads();
    }
    int excl = scn[t] - v;
    int node = b * CBUCKET + t;
    if (node < N_NODES) { row_start[node] = lo + excl; deg[node] = v; }
    cnt[t] = excl;                        // reuse as cursor
    __syncthreads();
    for (int i = lo + t; i < hi; i += 256) {
        unsigned e = edge8[i];
        int slot = atomicAdd(&cnt[e >> 24], 1);
        col[lo + slot] = (int)(e & 0xFFFFFF);   // src | x<<17 (24 bits)
    }
}

// ---- layer 1: h1 = relu(mean_j(embW1l[x_j]) + b1 + embW1r[x_i]) ----
// neighbor vocab ids come packed in col (bits 17..23): NO random x gather.
#define S1_NPW 8
__global__ __launch_bounds__(256) void sage1_kernel(
    const int* __restrict__ x, const float* __restrict__ embW1l,
    const float* __restrict__ embW1r, const float* __restrict__ b1,
    const int* __restrict__ row_start, const int* __restrict__ deg,
    const int* __restrict__ col, unsigned short* __restrict__ h1b)
{
    __shared__ float elds[VOCAB * 64];      // 32 KB -> 5 blocks/CU
    int t = threadIdx.x;
    for (int i = t * 4; i < VOCAB * 64; i += 1024)
        *(float4*)&elds[i] = *(const float4*)&embW1l[i];
    __syncthreads();

    int wave = t >> 6, lane = t & 63;
    int base_node = (blockIdx.x * 4 + wave) * S1_NPW;   // 3125*32 = 100000 exact
    float bias = b1[lane];

    int rs[S1_NPW], dgs[S1_NPW], cidx[S1_NPW], xn[S1_NPW];
    float self[S1_NPW];
#pragma unroll
    for (int n = 0; n < S1_NPW; ++n) {
        rs[n] = row_start[base_node + n];
        dgs[n] = deg[base_node + n];
        xn[n] = x[base_node + n];
    }
#pragma unroll
    for (int n = 0; n < S1_NPW; ++n) {
        cidx[n] = (lane < dgs[n]) ? col[rs[n] + lane] : 0;
        self[n] = embW1r[xn[n] * 64 + lane];
    }

    for (int n = 0; n < S1_NPW; ++n) {
        int node = base_node + n;
        int dg = dgs[n];
        int dgc = (dg < 64) ? dg : 64;

        float s0 = 0.f, s1 = 0.f, s2 = 0.f, s3 = 0.f;
        int j = 0;
        for (; j + 4 <= dgc; j += 4) {
            int x0 = __builtin_amdgcn_readlane(cidx[n], j + 0) >> 17;
            int x1 = __builtin_amdgcn_readlane(cidx[n], j + 1) >> 17;
            int x2 = __builtin_amdgcn_readlane(cidx[n], j + 2) >> 17;
            int x3 = __builtin_amdgcn_readlane(cidx[n], j + 3) >> 17;
            s0 += elds[x0 * 64 + lane];
            s1 += elds[x1 * 64 + lane];
            s2 += elds[x2 * 64 + lane];
            s3 += elds[x3 * 64 + lane];
        }
        for (; j < dgc; ++j) {
            int x0 = __builtin_amdgcn_readlane(cidx[n], j) >> 17;
            s0 += elds[x0 * 64 + lane];
        }
        for (int k = 64; k < dg; ++k) {                 // deg>64 tail (rare)
            int c = col[rs[n] + k];
            s0 += elds[(c >> 17) * 64 + lane];
        }
        float mean = ((s0 + s1) + (s2 + s3)) / fmaxf((float)dg, 1.0f);
        h1b[node * 64 + lane] = f2bf(fmaxf(mean + bias + self[n], 0.f));
    }
}

// ---- MFMA transform: [p|q] = h1 @ [W2l|W2r]  (M=100000, N=128, K=64) ----
// p stored fp8 e4m3 (gathered later -> smaller working set), q stored bf16.
__global__ __launch_bounds__(256) void mfma_transform_kernel(
    const unsigned short* __restrict__ h1b,
    const unsigned short* __restrict__ w2frag,
    unsigned char* __restrict__ p8, unsigned short* __restrict__ q16)
{
    int wave = threadIdx.x >> 6, lane = threadIdx.x & 63;
    int base16 = blockIdx.x * 64 + wave * 16;
    if (base16 >= N_NODES) return;                      // tail waves only
    int m = lane & 15, quad = lane >> 4;

    const unsigned short* arow = h1b + (base16 + m) * 64 + quad * 8;
    short8 a0 = *(const short8*)(arow);                 // k = 0..31
    short8 a1 = *(const short8*)(arow + 32);            // k = 32..63

#pragma unroll
    for (int tt = 0; tt < 8; ++tt) {                    // 8 output tiles of 16
        short8 b0 = *(const short8*)(w2frag + (tt * 1024 + 0)   + lane * 8);
        short8 b1 = *(const short8*)(w2frag + (tt * 1024 + 512) + lane * 8);
        f32x4 acc = {0.f, 0.f, 0.f, 0.f};
        acc = __builtin_amdgcn_mfma_f32_16x16x32_bf16(a0, b0, acc, 0, 0, 0);
        acc = __builtin_amdgcn_mfma_f32_16x16x32_bf16(a1, b1, acc, 0, 0, 0);
        int o = tt * 16 + m;
        if (o < 64) {
            // p: pack to fp8 e4m3 (rows i, i+1 share a pk convert)
            int pk01 = __builtin_amdgcn_cvt_pk_fp8_f32(acc[0], acc[1], 0, false);
            int pk23 = __builtin_amdgcn_cvt_pk_fp8_f32(acc[2], acc[3], 0, false);
            p8[(base16 + quad * 4 + 0) * 64 + o] = (unsigned char)(pk01 & 0xff);
            p8[(base16 + quad * 4 + 1) * 64 + o] = (unsigned char)((pk01 >> 8) & 0xff);
            p8[(base16 + quad * 4 + 2) * 64 + o] = (unsigned char)(pk23 & 0xff);
            p8[(base16 + quad * 4 + 3) * 64 + o] = (unsigned char)((pk23 >> 8) & 0xff);
        } else {
            int oc = o & 63;
#pragma unroll
            for (int i = 0; i < 4; ++i) {
                int node = base16 + quad * 4 + i;
                q16[node * 64 + oc] = f2bf(acc[i]);
            }
        }
    }
}

// ---- gather (r11-proven structure, fp8 rows): 4 features/lane, uint load --
//   h2 = relu(mean_j p_j + b2 + q_i);  gsum[batch] += h2 @ Wout
#define S2_NPW 8
__global__ __launch_bounds__(256, 8) void sage2_kernel(
    const unsigned char* __restrict__ p, const unsigned short* __restrict__ q,
    const int* __restrict__ row_start, const int* __restrict__ deg,
    const int* __restrict__ col, const float* __restrict__ b2,
    const float* __restrict__ Wout, const int* __restrict__ batch,
    float* __restrict__ gsum)
{
    int t = threadIdx.x;
    int wave = t >> 6, lane = t & 63;
    int base_node = (blockIdx.x * 4 + wave) * S2_NPW;   // exact cover
    int c = lane & 15;          // feature quad: features 4c..4c+3
    int g = lane >> 4;          // row group 0..3

    float4 b2v = ((const float4*)b2)[c];
    float4 w01 = ((const float4*)Wout)[c * 2];
    float4 w23 = ((const float4*)Wout)[c * 2 + 1];

    // prefetch per-node metadata + neighbor index rows for all 8 nodes
    int rs[S2_NPW], dgs[S2_NPW], cidx[S2_NPW];
#pragma unroll
    for (int n = 0; n < S2_NPW; ++n) {
        rs[n] = row_start[base_node + n];
        dgs[n] = deg[base_node + n];
    }
#pragma unroll
    for (int n = 0; n < S2_NPW; ++n)
        cidx[n] = (lane < dgs[n]) ? (col[rs[n] + lane] & 0x1FFFF) : 0;

    for (int n = 0; n < S2_NPW; ++n) {
        int node = base_node + n;
        int dg = dgs[n];
        int dgc = (dg < 64) ? dg : 64;

        // each iteration: 2 loads x 4 rows = 8 rows in flight (256 B each)
        float4 a0 = {0.f,0.f,0.f,0.f}, a1 = {0.f,0.f,0.f,0.f};
        for (int j = 0; j < dgc; j += 8) {
            int jj0 = j + g, jj1 = j + 4 + g;           // < 64 always
            int i0 = __shfl(cidx[n], jj0, 64);
            int i1 = __shfl(cidx[n], jj1, 64);
            unsigned v0 = *(const unsigned*)(p + i0 * 64 + c * 4);
            unsigned v1 = *(const unsigned*)(p + i1 * 64 + c * 4);
            if (jj0 < dgc) {
                a0.x += __builtin_amdgcn_cvt_f32_fp8(v0, 0);
                a0.y += __builtin_amdgcn_cvt_f32_fp8(v0, 1);
                a0.z += __builtin_amdgcn_cvt_f32_fp8(v0, 2);
                a0.w += __builtin_amdgcn_cvt_f32_fp8(v0, 3);
            }
            if (jj1 < dgc) {
                a1.x += __builtin_amdgcn_cvt_f32_fp8(v1, 0);
                a1.y += __builtin_amdgcn_cvt_f32_fp8(v1, 1);
                a1.z += __builtin_amdgcn_cvt_f32_fp8(v1, 2);
                a1.w += __builtin_amdgcn_cvt_f32_fp8(v1, 3);
            }
        }
        for (int k = 64; k < dg; ++k) {                 // deg>64 tail (rare)
            int r = col[rs[n] + k] & 0x1FFFF;
            unsigned v = *(const unsigned*)(p + r * 64 + c * 4);
            if (g == 0) {
                a0.x += __builtin_amdgcn_cvt_f32_fp8(v, 0);
                a0.y += __builtin_amdgcn_cvt_f32_fp8(v, 1);
                a0.z += __builtin_amdgcn_cvt_f32_fp8(v, 2);
                a0.w += __builtin_amdgcn_cvt_f32_fp8(v, 3);
            }
        }
        float sx = a0.x + a1.x, sy = a0.y + a1.y, sz = a0.z + a1.z, sw = a0.w + a1.w;
        // combine across the 4 row-groups (lanes {L, L^16, L^32, L^48})
        sx += __shfl_xor(sx, 16, 64); sx += __shfl_xor(sx, 32, 64);
        sy += __shfl_xor(sy, 16, 64); sy += __shfl_xor(sy, 32, 64);
        sz += __shfl_xor(sz, 16, 64); sz += __shfl_xor(sz, 32, 64);
        sw += __shfl_xor(sw, 16, 64); sw += __shfl_xor(sw, 32, 64);

        float inv = 1.0f / fmaxf((float)dg, 1.0f);
        ushort4 qv = *(const ushort4*)(q + node * 64 + c * 4);
        float h0 = fmaxf(sx * inv + b2v.x + bf2f(qv.x), 0.f);
        float h1 = fmaxf(sy * inv + b2v.y + bf2f(qv.y), 0.f);
        float h2 = fmaxf(sz * inv + b2v.z + bf2f(qv.z), 0.f);
        float h3 = fmaxf(sw * inv + b2v.w + bf2f(qv.w), 0.f);

        float p0 = h0 * w01.x + h1 * w01.z + h2 * w23.x + h3 * w23.z;
        float p1 = h0 * w01.y + h1 * w01.w + h2 * w23.y + h3 * w23.w;
        if (g != 0) { p0 = 0.f; p1 = 0.f; }             // groups duplicate
        p0 += __shfl_down(p0, 8, 64);  p1 += __shfl_down(p1, 8, 64);
        p0 += __shfl_down(p0, 4, 64);  p1 += __shfl_down(p1, 4, 64);
        p0 += __shfl_down(p0, 2, 64);  p1 += __shfl_down(p1, 2, 64);
        p0 += __shfl_down(p0, 1, 64);  p1 += __shfl_down(p1, 1, 64);
        if (lane == 0) {
            int grp = batch[node];
            atomicAdd(&gsum[grp * 2 + 0], p0);
            atomicAdd(&gsum[grp * 2 + 1], p1);
        }
    }
}

// ---------------- finalize: out = gsum/cnt + bout ----------------
__global__ __launch_bounds__(256) void finalize_kernel(
    const float* __restrict__ gsum, const int* __restrict__ gstart,
    const float* __restrict__ bout, float* __restrict__ out)
{
    int g = blockIdx.x * 256 + threadIdx.x;
    if (g >= N_GRAPHS) return;
    int cnt = gstart[g + 1] - gstart[g];
    float inv = 1.0f / fmaxf((float)cnt, 1.0f);
    out[g * 2 + 0] = gsum[g * 2 + 0] * inv + bout[0];
    out[g * 2 + 1] = gsum[g * 2 + 1] * inv + bout[1];
}

extern "C" void kernel_launch(void* const* d_in, const int* in_sizes, int n_in,
                              void* d_out, int out_size, void* d_ws, size_t ws_size,
                              hipStream_t stream) {
    const int*   x    = (const int*)  d_in[0];
    const int*   ei   = (const int*)  d_in[1];
    const int*   batch= (const int*)  d_in[2];
    const float* emb  = (const float*)d_in[3];
    const float* W1l  = (const float*)d_in[4];
    const float* b1   = (const float*)d_in[5];
    const float* W1r  = (const float*)d_in[6];
    const float* W2l  = (const float*)d_in[7];
    const float* b2   = (const float*)d_in[8];
    const float* W2r  = (const float*)d_in[9];
    const float* Wout = (const float*)d_in[10];
    const float* bout = (const float*)d_in[11];
    float* out = (float*)d_out;

    const int* src = ei;
    const int* dst = ei + N_EDGES;

    char* ws = (char*)d_ws;
    size_t off = 0;
    unsigned char*  p8     = (unsigned char*) (ws + off); off += (size_t)N_NODES * 64;      // 6.4 MB
    unsigned short* q16    = (unsigned short*)(ws + off); off += (size_t)N_NODES * 64 * 2;  // 12.8 MB
    unsigned short* h1b    = (unsigned short*)(ws + off); off += (size_t)N_NODES * 64 * 2;  // 12.8 MB
    unsigned short* w2frag = (unsigned short*)(ws + off); off += (size_t)8192 * 2;
    float*    embW1l = (float*)   (ws + off); off += (size_t)VOCAB * 64 * 4;
    float*    embW1r = (float*)   (ws + off); off += (size_t)VOCAB * 64 * 4;
    int*      rowst  = (int*)     (ws + off); off += (size_t)N_NODES * 4;
    int*      deg    = (int*)     (ws + off); off += (size_t)N_NODES * 4;
    int*      col    = (int*)     (ws + off); off += (size_t)(NBK * CAP + 256) * 4;   // 6.4 MB
    unsigned* edge8  = (unsigned*)(ws + off); off += (size_t)NBK * CAP * 4;           // 6.4 MB
    int*      cursor = (int*)     (ws + off); off += (size_t)NBK * 4;
    int*      gstart = (int*)     (ws + off); off += (size_t)(N_GRAPHS + 1) * 4;
    float*    gsum   = (float*)   (ws + off); off += (size_t)N_GRAPHS * 2 * 4;

    setup_kernel<<<GB + 32 + 1, 256, 0, stream>>>(
        batch, gstart, emb, W1l, W1r, W2l, W2r, embW1l, embW1r, w2frag,
        cursor, gsum);
    scatter_kernel<<<SCAT_BLOCKS, 256, 0, stream>>>(src, dst, x, cursor, edge8);
    csr_kernel<<<NBK, 256, 0, stream>>>(edge8, cursor, rowst, deg, col);
    sage1_kernel<<<N_NODES / (4 * S1_NPW), 256, 0, stream>>>(
        x, embW1l, embW1r, b1, rowst, deg, col, h1b);
    mfma_transform_kernel<<<(N_NODES + 63) / 64, 256, 0, stream>>>(
        h1b, w2frag, p8, q16);
    sage2_kernel<<<N_NODES / (4 * S2_NPW), 256, 0, stream>>>(
        p8, q16, rowst, deg, col, b2, Wout, batch, gsum);
    finalize_kernel<<<(N_GRAPHS + 255) / 256, 256, 0, stream>>>(gsum, gstart, bout, out);
}

// Round 15
// 210.485 us; speedup vs baseline: 1.2450x; 1.0345x over previous
//
#include <hip/hip_runtime.h>
#include <hip/hip_bf16.h>

#define N_NODES 100000
#define N_EDGES 1000000
#define EMB 64
#define HID 64
#define VOCAB 128
#define N_GRAPHS 2048

#define CBUCKET 256                                    // nodes per bucket
#define NBK ((N_NODES + CBUCKET - 1) / CBUCKET)        // 391
#define CAP 4096                                       // slots per bucket (E[cnt]=2560, 30 sigma)
#define CHUNK 4096
#define SCAT_BLOCKS ((N_EDGES + CHUNK - 1) / CHUNK)    // 245
#define GB ((N_NODES + 255) / 256)                     // 391 gstart blocks

#define BCASTF(v, l) __int_as_float(__builtin_amdgcn_readlane(__float_as_int(v), (l)))

typedef __attribute__((ext_vector_type(8))) short short8;
typedef __attribute__((ext_vector_type(4))) float f32x4;

__device__ __forceinline__ float bf2f(unsigned short u) {
    return __uint_as_float((unsigned)u << 16);
}
__device__ __forceinline__ unsigned short f2bf(float f) {
    return __bfloat16_as_ushort(__float2bfloat16(f));
}

// ---- merged scatter + setup: blocks [0,245) scatter, [245,636) gstart,
//      [636,668) precompute. cursor/gsum pre-zeroed by one memset.
__global__ __launch_bounds__(256) void scatter_kernel(
    const int* __restrict__ src, const int* __restrict__ dst,
    const int* __restrict__ x,
    int* __restrict__ cursor, unsigned* __restrict__ edge8,
    const int* __restrict__ batch, int* __restrict__ gstart,
    const float* __restrict__ emb, const float* __restrict__ W1l,
    const float* __restrict__ W1r,
    const float* __restrict__ W2l, const float* __restrict__ W2r,
    float* __restrict__ embW1l, float* __restrict__ embW1r,
    unsigned short* __restrict__ w2frag)
{
    __shared__ unsigned earr[CHUNK];            // 16 KB packed payload
    __shared__ unsigned short karr[CHUNK];      // 8 KB bucket key (0..390)
    __shared__ int bcnt[NBK];
    __shared__ int bbase[NBK];
    int b = blockIdx.x;
    int t = threadIdx.x;

    if (b < SCAT_BLOCKS) {
        // ---- scatter: LDS-staged chunk, per-(block,bucket) run reservation
        // 32-bit payload: src(17) | x[src](7, bits 17..23) | local_dst(8, bits 24..31)
        for (int i = t; i < NBK; i += 256) bcnt[i] = 0;
        __syncthreads();
        int e0 = b * CHUNK;
        int n = min(e0 + CHUNK, N_EDGES) - e0;
        for (int i = t; i < n; i += 256) {
            int d = dst[e0 + i];
            int s = src[e0 + i];
            int xv = x[s];                      // random 4B read, 400KB L2-hot
            int k = d >> 8;
            earr[i] = (unsigned)s | ((unsigned)xv << 17) | ((unsigned)(d & 255) << 24);
            karr[i] = (unsigned short)k;
            atomicAdd(&bcnt[k], 1);
        }
        __syncthreads();
        for (int i = t; i < NBK; i += 256) {
            int c = bcnt[i];
            bbase[i] = i * CAP + (c ? atomicAdd(&cursor[i], c) : 0);
            bcnt[i] = 0;                        // reuse as local cursor
        }
        __syncthreads();
        for (int i = t; i < n; i += 256) {
            int k = karr[i];
            int off = atomicAdd(&bcnt[k], 1);
            edge8[bbase[k] + off] = earr[i];    // dense single-writer runs
        }
    } else if (b < SCAT_BLOCKS + GB) {
        // ---- graph boundaries (batch sorted)
        int i = (b - SCAT_BLOCKS) * 256 + t;
        if (i >= N_NODES) return;
        int bg = batch[i];
        int bp = (i == 0) ? -1 : batch[i - 1];
        for (int g = bp + 1; g <= bg; ++g) gstart[g] = i;
        if (i == N_NODES - 1)
            for (int g = bg + 1; g <= N_GRAPHS; ++g) gstart[g] = N_NODES;
    } else {
        // ---- precompute embW1l/embW1r + pack W2 B-fragments
        int vb = b - SCAT_BLOCKS - GB;
        int wave = t >> 6, lane = t & 63;
        int v = vb * 4 + wave;
        if (v < VOCAB) {
            float er = emb[v * 64 + lane];       // lane = d
            float al = 0.f, ar = 0.f;
#pragma unroll 8
            for (int d = 0; d < 64; ++d) {
                float e = BCASTF(er, d);
                al += e * W1l[d * 64 + lane];
                ar += e * W1r[d * 64 + lane];
            }
            embW1l[v * 64 + lane] = al;
            embW1r[v * 64 + lane] = ar;
        }
        // W2 B-fragment packing: g = tt*1024 + h*512 + l*8 + j
        int g = vb * 256 + t;
        int j = g & 7, l = (g >> 3) & 63, h = (g >> 9) & 1, tt = g >> 10;
        int k = h * 32 + ((l >> 4) * 8) + j;
        int n = tt * 16 + (l & 15);
        float w = (n < 64) ? W2l[k * 64 + n] : W2r[k * 64 + (n - 64)];
        w2frag[g] = f2bf(w);
    }
}

// ---- per-bucket CSR build (rowstart/deg/col), dense writes ------
// col entry = src (17b) | x[src] (7b) -> sage1 needs no x gather at all
__global__ __launch_bounds__(256) void csr_kernel(
    const unsigned* __restrict__ edge8, const int* __restrict__ cursor,
    int* __restrict__ row_start, int* __restrict__ deg, int* __restrict__ col)
{
    __shared__ int cnt[CBUCKET];
    __shared__ int scn[CBUCKET];
    int b = blockIdx.x;                   // NBK blocks
    int t = threadIdx.x;
    int lo = b * CAP, hi = lo + cursor[b];  // cursor holds final fill count
    cnt[t] = 0;
    __syncthreads();
    for (int i = lo + t; i < hi; i += 256)
        atomicAdd(&cnt[edge8[i] >> 24], 1);
    __syncthreads();
    int v = cnt[t];
    scn[t] = v;
    __syncthreads();
    for (int off = 1; off < 256; off <<= 1) {
        int tmp = (t >= off) ? scn[t - off] : 0;
        __syncthreads();
        scn[t] += tmp;
        __syncthreads();
    }
    int excl = scn[t] - v;
    int node = b * CBUCKET + t;
    if (node < N_NODES) { row_start[node] = lo + excl; deg[node] = v; }
    cnt[t] = excl;                        // reuse as cursor
    __syncthreads();
    for (int i = lo + t; i < hi; i += 256) {
        unsigned e = edge8[i];
        int slot = atomicAdd(&cnt[e >> 24], 1);
        col[lo + slot] = (int)(e & 0xFFFFFF);   // src | x<<17 (24 bits)
    }
}

// ---- fused layer 1 + MFMA transform:
//   phase A: h1 = relu(mean_j(embW1l[x_j]) + b1 + embW1r[x_i])  (regs)
//   phase B: [p|q] = h1 @ [W2l|W2r] via mfma_16x16x32_bf16; msbuf aliases elds
#define S1_NPW 8
__global__ __launch_bounds__(256) void sage1_kernel(
    const int* __restrict__ x, const float* __restrict__ embW1l,
    const float* __restrict__ embW1r, const float* __restrict__ b1,
    const int* __restrict__ row_start, const int* __restrict__ deg,
    const int* __restrict__ col, const unsigned short* __restrict__ w2frag,
    unsigned char* __restrict__ p8, unsigned short* __restrict__ q16)
{
    __shared__ float elds[VOCAB * 64];      // 32 KB; phase B aliases as msbuf
    int t = threadIdx.x;
    for (int i = t * 4; i < VOCAB * 64; i += 1024)
        *(float4*)&elds[i] = *(const float4*)&embW1l[i];
    __syncthreads();

    int wave = t >> 6, lane = t & 63;
    int block_base = blockIdx.x * (4 * S1_NPW);         // 3125*32 = 100000 exact
    int base_node = block_base + wave * S1_NPW;
    float bias = b1[lane];

    int rs[S1_NPW], dgs[S1_NPW], cidx[S1_NPW], xn[S1_NPW];
    float self[S1_NPW];
#pragma unroll
    for (int n = 0; n < S1_NPW; ++n) {
        rs[n] = row_start[base_node + n];
        dgs[n] = deg[base_node + n];
        xn[n] = x[base_node + n];
    }
#pragma unroll
    for (int n = 0; n < S1_NPW; ++n) {
        cidx[n] = (lane < dgs[n]) ? col[rs[n] + lane] : 0;
        self[n] = embW1r[xn[n] * 64 + lane];
    }

    float h1v[S1_NPW];
    for (int n = 0; n < S1_NPW; ++n) {
        int dg = dgs[n];
        int dgc = (dg < 64) ? dg : 64;

        float s0 = 0.f, s1 = 0.f, s2 = 0.f, s3 = 0.f;
        int j = 0;
        for (; j + 4 <= dgc; j += 4) {
            int x0 = __builtin_amdgcn_readlane(cidx[n], j + 0) >> 17;
            int x1 = __builtin_amdgcn_readlane(cidx[n], j + 1) >> 17;
            int x2 = __builtin_amdgcn_readlane(cidx[n], j + 2) >> 17;
            int x3 = __builtin_amdgcn_readlane(cidx[n], j + 3) >> 17;
            s0 += elds[x0 * 64 + lane];
            s1 += elds[x1 * 64 + lane];
            s2 += elds[x2 * 64 + lane];
            s3 += elds[x3 * 64 + lane];
        }
        for (; j < dgc; ++j) {
            int x0 = __builtin_amdgcn_readlane(cidx[n], j) >> 17;
            s0 += elds[x0 * 64 + lane];
        }
        for (int k = 64; k < dg; ++k) {                 // deg>64 tail (rare)
            int c = col[rs[n] + k];
            s0 += elds[(c >> 17) * 64 + lane];
        }
        float mean = ((s0 + s1) + (s2 + s3)) / fmaxf((float)dg, 1.0f);
        h1v[n] = fmaxf(mean + bias + self[n], 0.f);
    }
    __syncthreads();                        // all elds reads complete

    // stage h1 rows (bf16) into msbuf aliasing elds; stride 72 -> 16B-aligned rows
    unsigned short* msbuf = (unsigned short*)elds;      // [32][72]
#pragma unroll
    for (int n = 0; n < S1_NPW; ++n)
        msbuf[(wave * S1_NPW + n) * 72 + lane] = f2bf(h1v[n]);
    __syncthreads();

    // phase B: wave -> node-group (wave>>1), output tiles (wave&1)*4..+3
    int grp = wave >> 1, tbase = (wave & 1) * 4;
    int m = lane & 15, quad = lane >> 4;
    int base16g = block_base + grp * 16;
    const unsigned short* arow = &msbuf[(grp * 16 + m) * 72 + quad * 8];
    short8 a0 = *(const short8*)(arow);                 // k = quad*8 .. +7
    short8 a1 = *(const short8*)(arow + 32);            // k = 32+quad*8 .. +7

#pragma unroll
    for (int tt = tbase; tt < tbase + 4; ++tt) {
        short8 b0 = *(const short8*)(w2frag + tt * 1024 + lane * 8);
        short8 b1v = *(const short8*)(w2frag + tt * 1024 + 512 + lane * 8);
        f32x4 acc = {0.f, 0.f, 0.f, 0.f};
        acc = __builtin_amdgcn_mfma_f32_16x16x32_bf16(a0, b0, acc, 0, 0, 0);
        acc = __builtin_amdgcn_mfma_f32_16x16x32_bf16(a1, b1v, acc, 0, 0, 0);
        int o = tt * 16 + m;
        if (o < 64) {
            int pk01 = __builtin_amdgcn_cvt_pk_fp8_f32(acc[0], acc[1], 0, false);
            int pk23 = __builtin_amdgcn_cvt_pk_fp8_f32(acc[2], acc[3], 0, false);
            p8[(base16g + quad * 4 + 0) * 64 + o] = (unsigned char)(pk01 & 0xff);
            p8[(base16g + quad * 4 + 1) * 64 + o] = (unsigned char)((pk01 >> 8) & 0xff);
            p8[(base16g + quad * 4 + 2) * 64 + o] = (unsigned char)(pk23 & 0xff);
            p8[(base16g + quad * 4 + 3) * 64 + o] = (unsigned char)((pk23 >> 8) & 0xff);
        } else {
            int oc = o & 63;
#pragma unroll
            for (int i = 0; i < 4; ++i)
                q16[(base16g + quad * 4 + i) * 64 + oc] = f2bf(acc[i]);
        }
    }
}

// ---- gather (r11-proven structure, fp8 rows): 4 features/lane, uint load --
//   h2 = relu(mean_j p_j + b2 + q_i);  gsum[batch] += h2 @ Wout
#define S2_NPW 8
__global__ __launch_bounds__(256, 6) void sage2_kernel(
    const unsigned char* __restrict__ p, const unsigned short* __restrict__ q,
    const int* __restrict__ row_start, const int* __restrict__ deg,
    const int* __restrict__ col, const float* __restrict__ b2,
    const float* __restrict__ Wout, const int* __restrict__ batch,
    float* __restrict__ gsum)
{
    int t = threadIdx.x;
    int wave = t >> 6, lane = t & 63;
    int base_node = (blockIdx.x * 4 + wave) * S2_NPW;   // exact cover
    int c = lane & 15;          // feature quad: features 4c..4c+3
    int g = lane >> 4;          // row group 0..3

    float4 b2v = ((const float4*)b2)[c];
    float4 w01 = ((const float4*)Wout)[c * 2];
    float4 w23 = ((const float4*)Wout)[c * 2 + 1];

    // prefetch per-node metadata + neighbor index rows for all 8 nodes
    int rs[S2_NPW], dgs[S2_NPW], cidx[S2_NPW];
#pragma unroll
    for (int n = 0; n < S2_NPW; ++n) {
        rs[n] = row_start[base_node + n];
        dgs[n] = deg[base_node + n];
    }
#pragma unroll
    for (int n = 0; n < S2_NPW; ++n)
        cidx[n] = (lane < dgs[n]) ? (col[rs[n] + lane] & 0x1FFFF) : 0;

    for (int n = 0; n < S2_NPW; ++n) {
        int node = base_node + n;
        int dg = dgs[n];
        int dgc = (dg < 64) ? dg : 64;

        // each iteration: 2 loads x 4 rows = 8 rows in flight (256 B each)
        float4 a0 = {0.f,0.f,0.f,0.f}, a1 = {0.f,0.f,0.f,0.f};
        for (int j = 0; j < dgc; j += 8) {
            int jj0 = j + g, jj1 = j + 4 + g;           // < 64 always
            int i0 = __shfl(cidx[n], jj0, 64);
            int i1 = __shfl(cidx[n], jj1, 64);
            unsigned v0 = *(const unsigned*)(p + i0 * 64 + c * 4);
            unsigned v1 = *(const unsigned*)(p + i1 * 64 + c * 4);
            if (jj0 < dgc) {
                a0.x += __builtin_amdgcn_cvt_f32_fp8(v0, 0);
                a0.y += __builtin_amdgcn_cvt_f32_fp8(v0, 1);
                a0.z += __builtin_amdgcn_cvt_f32_fp8(v0, 2);
                a0.w += __builtin_amdgcn_cvt_f32_fp8(v0, 3);
            }
            if (jj1 < dgc) {
                a1.x += __builtin_amdgcn_cvt_f32_fp8(v1, 0);
                a1.y += __builtin_amdgcn_cvt_f32_fp8(v1, 1);
                a1.z += __builtin_amdgcn_cvt_f32_fp8(v1, 2);
                a1.w += __builtin_amdgcn_cvt_f32_fp8(v1, 3);
            }
        }
        for (int k = 64; k < dg; ++k) {                 // deg>64 tail (rare)
            int r = col[rs[n] + k] & 0x1FFFF;
            unsigned v = *(const unsigned*)(p + r * 64 + c * 4);
            if (g == 0) {
                a0.x += __builtin_amdgcn_cvt_f32_fp8(v, 0);
                a0.y += __builtin_amdgcn_cvt_f32_fp8(v, 1);
                a0.z += __builtin_amdgcn_cvt_f32_fp8(v, 2);
                a0.w += __builtin_amdgcn_cvt_f32_fp8(v, 3);
            }
        }
        float sx = a0.x + a1.x, sy = a0.y + a1.y, sz = a0.z + a1.z, sw = a0.w + a1.w;
        // combine across the 4 row-groups (lanes {L, L^16, L^32, L^48})
        sx += __shfl_xor(sx, 16, 64); sx += __shfl_xor(sx, 32, 64);
        sy += __shfl_xor(sy, 16, 64); sy += __shfl_xor(sy, 32, 64);
        sz += __shfl_xor(sz, 16, 64); sz += __shfl_xor(sz, 32, 64);
        sw += __shfl_xor(sw, 16, 64); sw += __shfl_xor(sw, 32, 64);

        float inv = 1.0f / fmaxf((float)dg, 1.0f);
        ushort4 qv = *(const ushort4*)(q + node * 64 + c * 4);
        float h0 = fmaxf(sx * inv + b2v.x + bf2f(qv.x), 0.f);
        float h1 = fmaxf(sy * inv + b2v.y + bf2f(qv.y), 0.f);
        float h2 = fmaxf(sz * inv + b2v.z + bf2f(qv.z), 0.f);
        float h3 = fmaxf(sw * inv + b2v.w + bf2f(qv.w), 0.f);

        float p0 = h0 * w01.x + h1 * w01.z + h2 * w23.x + h3 * w23.z;
        float p1 = h0 * w01.y + h1 * w01.w + h2 * w23.y + h3 * w23.w;
        if (g != 0) { p0 = 0.f; p1 = 0.f; }             // groups duplicate
        p0 += __shfl_down(p0, 8, 64);  p1 += __shfl_down(p1, 8, 64);
        p0 += __shfl_down(p0, 4, 64);  p1 += __shfl_down(p1, 4, 64);
        p0 += __shfl_down(p0, 2, 64);  p1 += __shfl_down(p1, 2, 64);
        p0 += __shfl_down(p0, 1, 64);  p1 += __shfl_down(p1, 1, 64);
        if (lane == 0) {
            int grp = batch[node];
            atomicAdd(&gsum[grp * 2 + 0], p0);
            atomicAdd(&gsum[grp * 2 + 1], p1);
        }
    }
}

// ---------------- finalize: out = gsum/cnt + bout ----------------
__global__ __launch_bounds__(256) void finalize_kernel(
    const float* __restrict__ gsum, const int* __restrict__ gstart,
    const float* __restrict__ bout, float* __restrict__ out)
{
    int g = blockIdx.x * 256 + threadIdx.x;
    if (g >= N_GRAPHS) return;
    int cnt = gstart[g + 1] - gstart[g];
    float inv = 1.0f / fmaxf((float)cnt, 1.0f);
    out[g * 2 + 0] = gsum[g * 2 + 0] * inv + bout[0];
    out[g * 2 + 1] = gsum[g * 2 + 1] * inv + bout[1];
}

extern "C" void kernel_launch(void* const* d_in, const int* in_sizes, int n_in,
                              void* d_out, int out_size, void* d_ws, size_t ws_size,
                              hipStream_t stream) {
    const int*   x    = (const int*)  d_in[0];
    const int*   ei   = (const int*)  d_in[1];
    const int*   batch= (const int*)  d_in[2];
    const float* emb  = (const float*)d_in[3];
    const float* W1l  = (const float*)d_in[4];
    const float* b1   = (const float*)d_in[5];
    const float* W1r  = (const float*)d_in[6];
    const float* W2l  = (const float*)d_in[7];
    const float* b2   = (const float*)d_in[8];
    const float* W2r  = (const float*)d_in[9];
    const float* Wout = (const float*)d_in[10];
    const float* bout = (const float*)d_in[11];
    float* out = (float*)d_out;

    const int* src = ei;
    const int* dst = ei + N_EDGES;

    char* ws = (char*)d_ws;
    size_t off = 0;
    unsigned char*  p8     = (unsigned char*) (ws + off); off += (size_t)N_NODES * 64;      // 6.4 MB
    unsigned short* q16    = (unsigned short*)(ws + off); off += (size_t)N_NODES * 64 * 2;  // 12.8 MB
    unsigned short* w2frag = (unsigned short*)(ws + off); off += (size_t)8192 * 2;
    float*    embW1l = (float*)   (ws + off); off += (size_t)VOCAB * 64 * 4;
    float*    embW1r = (float*)   (ws + off); off += (size_t)VOCAB * 64 * 4;
    int*      rowst  = (int*)     (ws + off); off += (size_t)N_NODES * 4;
    int*      deg    = (int*)     (ws + off); off += (size_t)N_NODES * 4;
    int*      col    = (int*)     (ws + off); off += (size_t)(NBK * CAP + 256) * 4;   // 6.4 MB
    unsigned* edge8  = (unsigned*)(ws + off); off += (size_t)NBK * CAP * 4;           // 6.4 MB
    int*      gstart = (int*)     (ws + off); off += (size_t)(N_GRAPHS + 1) * 4;
    // contiguous zero region: cursor | gsum (one memset)
    int*      cursor = (int*)     (ws + off); off += (size_t)NBK * 4;
    float*    gsum   = (float*)   (ws + off); off += (size_t)N_GRAPHS * 2 * 4;

    hipMemsetAsync(cursor, 0, (size_t)NBK * 4 + (size_t)N_GRAPHS * 2 * 4, stream);

    scatter_kernel<<<SCAT_BLOCKS + GB + 32, 256, 0, stream>>>(
        src, dst, x, cursor, edge8,
        batch, gstart, emb, W1l, W1r, W2l, W2r, embW1l, embW1r, w2frag);
    csr_kernel<<<NBK, 256, 0, stream>>>(edge8, cursor, rowst, deg, col);
    sage1_kernel<<<N_NODES / (4 * S1_NPW), 256, 0, stream>>>(
        x, embW1l, embW1r, b1, rowst, deg, col, w2frag, p8, q16);
    sage2_kernel<<<N_NODES / (4 * S2_NPW), 256, 0, stream>>>(
        p8, q16, rowst, deg, col, b2, Wout, batch, gsum);
    finalize_kernel<<<(N_GRAPHS + 255) / 256, 256, 0, stream>>>(gsum, gstart, bout, out);
}

// Round 16
// 208.050 us; speedup vs baseline: 1.2595x; 1.0117x over previous
//
#include <hip/hip_runtime.h>
#include <hip/hip_bf16.h>

#define N_NODES 100000
#define N_EDGES 1000000
#define EMB 64
#define HID 64
#define VOCAB 128
#define N_GRAPHS 2048

#define CBUCKET 256                                    // nodes per bucket
#define NBK ((N_NODES + CBUCKET - 1) / CBUCKET)        // 391
#define CAP 4096                                       // slots per bucket (E[cnt]=2560, 30 sigma)
#define CHUNK 4096
#define SCAT_BLOCKS ((N_EDGES + CHUNK - 1) / CHUNK)    // 245
#define GB ((N_NODES + 255) / 256)                     // 391 gstart blocks

#define BCASTF(v, l) __int_as_float(__builtin_amdgcn_readlane(__float_as_int(v), (l)))

typedef __attribute__((ext_vector_type(8))) short short8;
typedef __attribute__((ext_vector_type(4))) float f32x4;

__device__ __forceinline__ float bf2f(unsigned short u) {
    return __uint_as_float((unsigned)u << 16);
}
__device__ __forceinline__ unsigned short f2bf(float f) {
    return __bfloat16_as_ushort(__float2bfloat16(f));
}

// ---- merged scatter + setup: blocks [0,245) scatter, [245,636) gstart,
//      [636,668) precompute. cursor/gsum pre-zeroed by one memset.
__global__ __launch_bounds__(256) void scatter_kernel(
    const int* __restrict__ src, const int* __restrict__ dst,
    const int* __restrict__ x,
    int* __restrict__ cursor, unsigned* __restrict__ edge8,
    const int* __restrict__ batch, int* __restrict__ gstart,
    const float* __restrict__ emb, const float* __restrict__ W1l,
    const float* __restrict__ W1r,
    const float* __restrict__ W2l, const float* __restrict__ W2r,
    float* __restrict__ embW1l, float* __restrict__ embW1r,
    unsigned short* __restrict__ w2frag)
{
    __shared__ unsigned earr[CHUNK];            // 16 KB packed payload
    __shared__ unsigned short karr[CHUNK];      // 8 KB bucket key (0..390)
    __shared__ int bcnt[NBK];
    __shared__ int bbase[NBK];
    int b = blockIdx.x;
    int t = threadIdx.x;

    if (b < SCAT_BLOCKS) {
        // ---- scatter: LDS-staged chunk, per-(block,bucket) run reservation
        // 32-bit payload: src(17) | x[src](7, bits 17..23) | local_dst(8, bits 24..31)
        for (int i = t; i < NBK; i += 256) bcnt[i] = 0;
        __syncthreads();
        int e0 = b * CHUNK;
        int n = min(e0 + CHUNK, N_EDGES) - e0;
        for (int i = t; i < n; i += 256) {
            int d = dst[e0 + i];
            int s = src[e0 + i];
            int xv = x[s];                      // random 4B read, 400KB L2-hot
            int k = d >> 8;
            earr[i] = (unsigned)s | ((unsigned)xv << 17) | ((unsigned)(d & 255) << 24);
            karr[i] = (unsigned short)k;
            atomicAdd(&bcnt[k], 1);
        }
        __syncthreads();
        for (int i = t; i < NBK; i += 256) {
            int c = bcnt[i];
            bbase[i] = i * CAP + (c ? atomicAdd(&cursor[i], c) : 0);
            bcnt[i] = 0;                        // reuse as local cursor
        }
        __syncthreads();
        for (int i = t; i < n; i += 256) {
            int k = karr[i];
            int off = atomicAdd(&bcnt[k], 1);
            edge8[bbase[k] + off] = earr[i];    // dense single-writer runs
        }
    } else if (b < SCAT_BLOCKS + GB) {
        // ---- graph boundaries (batch sorted)
        int i = (b - SCAT_BLOCKS) * 256 + t;
        if (i >= N_NODES) return;
        int bg = batch[i];
        int bp = (i == 0) ? -1 : batch[i - 1];
        for (int g = bp + 1; g <= bg; ++g) gstart[g] = i;
        if (i == N_NODES - 1)
            for (int g = bg + 1; g <= N_GRAPHS; ++g) gstart[g] = N_NODES;
    } else {
        // ---- precompute embW1l/embW1r + pack W2 B-fragments
        int vb = b - SCAT_BLOCKS - GB;
        int wave = t >> 6, lane = t & 63;
        int v = vb * 4 + wave;
        if (v < VOCAB) {
            float er = emb[v * 64 + lane];       // lane = d
            float al = 0.f, ar = 0.f;
#pragma unroll 8
            for (int d = 0; d < 64; ++d) {
                float e = BCASTF(er, d);
                al += e * W1l[d * 64 + lane];
                ar += e * W1r[d * 64 + lane];
            }
            embW1l[v * 64 + lane] = al;
            embW1r[v * 64 + lane] = ar;
        }
        // W2 B-fragment packing: g = tt*1024 + h*512 + l*8 + j
        int g = vb * 256 + t;
        int j = g & 7, l = (g >> 3) & 63, h = (g >> 9) & 1, tt = g >> 10;
        int k = h * 32 + ((l >> 4) * 8) + j;
        int n = tt * 16 + (l & 15);
        float w = (n < 64) ? W2l[k * 64 + n] : W2r[k * 64 + (n - 64)];
        w2frag[g] = f2bf(w);
    }
}

// ---- per-bucket CSR build (rowstart/deg/col), dense writes ------
// col entry = src (17b) | x[src] (7b) -> sage1 needs no x gather at all
__global__ __launch_bounds__(256) void csr_kernel(
    const unsigned* __restrict__ edge8, const int* __restrict__ cursor,
    int* __restrict__ row_start, int* __restrict__ deg, int* __restrict__ col)
{
    __shared__ int cnt[CBUCKET];
    __shared__ int scn[CBUCKET];
    int b = blockIdx.x;                   // NBK blocks
    int t = threadIdx.x;
    int lo = b * CAP, hi = lo + cursor[b];  // cursor holds final fill count
    cnt[t] = 0;
    __syncthreads();
    for (int i = lo + t; i < hi; i += 256)
        atomicAdd(&cnt[edge8[i] >> 24], 1);
    __syncthreads();
    int v = cnt[t];
    scn[t] = v;
    __syncthreads();
    for (int off = 1; off < 256; off <<= 1) {
        int tmp = (t >= off) ? scn[t - off] : 0;
        __syncthreads();
        scn[t] += tmp;
        __syncthreads();
    }
    int excl = scn[t] - v;
    int node = b * CBUCKET + t;
    if (node < N_NODES) { row_start[node] = lo + excl; deg[node] = v; }
    cnt[t] = excl;                        // reuse as cursor
    __syncthreads();
    for (int i = lo + t; i < hi; i += 256) {
        unsigned e = edge8[i];
        int slot = atomicAdd(&cnt[e >> 24], 1);
        col[lo + slot] = (int)(e & 0xFFFFFF);   // src | x<<17 (24 bits)
    }
}

// ---- fused layer 1 + MFMA transform:
//   phase A: h1 = relu(mean_j(embW1l[x_j]) + b1 + embW1r[x_i])  ((c,g) layout,
//            ds_read_b128: one wave-instr covers 4 rows, 8 rows in flight)
//   phase B: [p|q] = h1 @ [W2l|W2r] via mfma_16x16x32_bf16; msbuf aliases elds
#define S1_NPW 8
__global__ __launch_bounds__(256) void sage1_kernel(
    const int* __restrict__ x, const float* __restrict__ embW1l,
    const float* __restrict__ embW1r, const float* __restrict__ b1,
    const int* __restrict__ row_start, const int* __restrict__ deg,
    const int* __restrict__ col, const unsigned short* __restrict__ w2frag,
    unsigned char* __restrict__ p8, unsigned short* __restrict__ q16)
{
    __shared__ float elds[VOCAB * 64];      // 32 KB; phase B aliases as msbuf
    int t = threadIdx.x;
    for (int i = t * 4; i < VOCAB * 64; i += 1024)
        *(float4*)&elds[i] = *(const float4*)&embW1l[i];
    __syncthreads();

    int wave = t >> 6, lane = t & 63;
    int block_base = blockIdx.x * (4 * S1_NPW);         // 3125*32 = 100000 exact
    int base_node = block_base + wave * S1_NPW;
    int c = lane & 15;          // feature quad: features 4c..4c+3
    int g = lane >> 4;          // row group 0..3
    float4 bias4 = ((const float4*)b1)[c];

    int rs[S1_NPW], dgs[S1_NPW], cidx[S1_NPW], xn[S1_NPW];
    float4 self4[S1_NPW];
#pragma unroll
    for (int n = 0; n < S1_NPW; ++n) {
        rs[n] = row_start[base_node + n];
        dgs[n] = deg[base_node + n];
        xn[n] = x[base_node + n];
    }
#pragma unroll
    for (int n = 0; n < S1_NPW; ++n) {
        cidx[n] = (lane < dgs[n]) ? col[rs[n] + lane] : 0;
        self4[n] = ((const float4*)(embW1r + xn[n] * 64))[c];
    }

    unsigned short* msbuf = (unsigned short*)elds;      // [32][72], aliases elds
    ushort4 h1row[S1_NPW];                              // lane's 4 features per node

    for (int n = 0; n < S1_NPW; ++n) {
        int dg = dgs[n];
        int dgc = (dg < 64) ? dg : 64;

        // 2 x ds_read_b128 per iter; each covers 4 rows across the groups
        float4 a0 = {0.f,0.f,0.f,0.f}, a1 = {0.f,0.f,0.f,0.f};
        for (int j = 0; j < dgc; j += 8) {
            int jj0 = j + g, jj1 = j + 4 + g;           // < 64 always
            int x0 = __shfl(cidx[n], jj0, 64) >> 17;
            int x1 = __shfl(cidx[n], jj1, 64) >> 17;
            float4 v0 = *(const float4*)&elds[x0 * 64 + c * 4];
            float4 v1 = *(const float4*)&elds[x1 * 64 + c * 4];
            if (jj0 < dgc) { a0.x += v0.x; a0.y += v0.y; a0.z += v0.z; a0.w += v0.w; }
            if (jj1 < dgc) { a1.x += v1.x; a1.y += v1.y; a1.z += v1.z; a1.w += v1.w; }
        }
        for (int k = 64; k < dg; ++k) {                 // deg>64 tail (rare)
            int cc = col[rs[n] + k] >> 17;
            float4 v = *(const float4*)&elds[cc * 64 + c * 4];
            if (g == 0) { a0.x += v.x; a0.y += v.y; a0.z += v.z; a0.w += v.w; }
        }
        float sx = a0.x + a1.x, sy = a0.y + a1.y, sz = a0.z + a1.z, sw = a0.w + a1.w;
        sx += __shfl_xor(sx, 16, 64); sx += __shfl_xor(sx, 32, 64);
        sy += __shfl_xor(sy, 16, 64); sy += __shfl_xor(sy, 32, 64);
        sz += __shfl_xor(sz, 16, 64); sz += __shfl_xor(sz, 32, 64);
        sw += __shfl_xor(sw, 16, 64); sw += __shfl_xor(sw, 32, 64);

        float inv = 1.0f / fmaxf((float)dg, 1.0f);
        h1row[n].x = f2bf(fmaxf(sx * inv + bias4.x + self4[n].x, 0.f));
        h1row[n].y = f2bf(fmaxf(sy * inv + bias4.y + self4[n].y, 0.f));
        h1row[n].z = f2bf(fmaxf(sz * inv + bias4.z + self4[n].z, 0.f));
        h1row[n].w = f2bf(fmaxf(sw * inv + bias4.w + self4[n].w, 0.f));
    }
    __syncthreads();                        // all elds reads complete

    // stage h1 rows into msbuf (stride 72 -> 16B-aligned rows); g==0 writes
    if (g == 0) {
#pragma unroll
        for (int n = 0; n < S1_NPW; ++n)
            *(ushort4*)&msbuf[(wave * S1_NPW + n) * 72 + c * 4] = h1row[n];
    }
    __syncthreads();

    // phase B: wave -> node-group (wave>>1), output tiles (wave&1)*4..+3
    int grp = wave >> 1, tbase = (wave & 1) * 4;
    int m = lane & 15, quad = lane >> 4;
    int base16g = block_base + grp * 16;
    const unsigned short* arow = &msbuf[(grp * 16 + m) * 72 + quad * 8];
    short8 a0 = *(const short8*)(arow);                 // k = quad*8 .. +7
    short8 a1 = *(const short8*)(arow + 32);            // k = 32+quad*8 .. +7

#pragma unroll
    for (int tt = tbase; tt < tbase + 4; ++tt) {
        short8 b0 = *(const short8*)(w2frag + tt * 1024 + lane * 8);
        short8 b1v = *(const short8*)(w2frag + tt * 1024 + 512 + lane * 8);
        f32x4 acc = {0.f, 0.f, 0.f, 0.f};
        acc = __builtin_amdgcn_mfma_f32_16x16x32_bf16(a0, b0, acc, 0, 0, 0);
        acc = __builtin_amdgcn_mfma_f32_16x16x32_bf16(a1, b1v, acc, 0, 0, 0);
        int o = tt * 16 + m;
        if (o < 64) {
            int pk01 = __builtin_amdgcn_cvt_pk_fp8_f32(acc[0], acc[1], 0, false);
            int pk23 = __builtin_amdgcn_cvt_pk_fp8_f32(acc[2], acc[3], 0, false);
            p8[(base16g + quad * 4 + 0) * 64 + o] = (unsigned char)(pk01 & 0xff);
            p8[(base16g + quad * 4 + 1) * 64 + o] = (unsigned char)((pk01 >> 8) & 0xff);
            p8[(base16g + quad * 4 + 2) * 64 + o] = (unsigned char)(pk23 & 0xff);
            p8[(base16g + quad * 4 + 3) * 64 + o] = (unsigned char)((pk23 >> 8) & 0xff);
        } else {
            int oc = o & 63;
#pragma unroll
            for (int i = 0; i < 4; ++i)
                q16[(base16g + quad * 4 + i) * 64 + oc] = f2bf(acc[i]);
        }
    }
}

// ---- gather (r11-proven structure, fp8 rows): 4 features/lane, uint load --
//   h2 = relu(mean_j p_j + b2 + q_i);  gsum[batch] += h2 @ Wout
#define S2_NPW 8
__global__ __launch_bounds__(256, 6) void sage2_kernel(
    const unsigned char* __restrict__ p, const unsigned short* __restrict__ q,
    const int* __restrict__ row_start, const int* __restrict__ deg,
    const int* __restrict__ col, const float* __restrict__ b2,
    const float* __restrict__ Wout, const int* __restrict__ batch,
    float* __restrict__ gsum)
{
    int t = threadIdx.x;
    int wave = t >> 6, lane = t & 63;
    int base_node = (blockIdx.x * 4 + wave) * S2_NPW;   // exact cover
    int c = lane & 15;          // feature quad: features 4c..4c+3
    int g = lane >> 4;          // row group 0..3

    float4 b2v = ((const float4*)b2)[c];
    float4 w01 = ((const float4*)Wout)[c * 2];
    float4 w23 = ((const float4*)Wout)[c * 2 + 1];

    // prefetch per-node metadata + neighbor index rows for all 8 nodes
    int rs[S2_NPW], dgs[S2_NPW], cidx[S2_NPW];
#pragma unroll
    for (int n = 0; n < S2_NPW; ++n) {
        rs[n] = row_start[base_node + n];
        dgs[n] = deg[base_node + n];
    }
#pragma unroll
    for (int n = 0; n < S2_NPW; ++n)
        cidx[n] = (lane < dgs[n]) ? (col[rs[n] + lane] & 0x1FFFF) : 0;

    for (int n = 0; n < S2_NPW; ++n) {
        int node = base_node + n;
        int dg = dgs[n];
        int dgc = (dg < 64) ? dg : 64;

        // each iteration: 2 loads x 4 rows = 8 rows in flight (256 B each)
        float4 a0 = {0.f,0.f,0.f,0.f}, a1 = {0.f,0.f,0.f,0.f};
        for (int j = 0; j < dgc; j += 8) {
            int jj0 = j + g, jj1 = j + 4 + g;           // < 64 always
            int i0 = __shfl(cidx[n], jj0, 64);
            int i1 = __shfl(cidx[n], jj1, 64);
            unsigned v0 = *(const unsigned*)(p + i0 * 64 + c * 4);
            unsigned v1 = *(const unsigned*)(p + i1 * 64 + c * 4);
            if (jj0 < dgc) {
                a0.x += __builtin_amdgcn_cvt_f32_fp8(v0, 0);
                a0.y += __builtin_amdgcn_cvt_f32_fp8(v0, 1);
                a0.z += __builtin_amdgcn_cvt_f32_fp8(v0, 2);
                a0.w += __builtin_amdgcn_cvt_f32_fp8(v0, 3);
            }
            if (jj1 < dgc) {
                a1.x += __builtin_amdgcn_cvt_f32_fp8(v1, 0);
                a1.y += __builtin_amdgcn_cvt_f32_fp8(v1, 1);
                a1.z += __builtin_amdgcn_cvt_f32_fp8(v1, 2);
                a1.w += __builtin_amdgcn_cvt_f32_fp8(v1, 3);
            }
        }
        for (int k = 64; k < dg; ++k) {                 // deg>64 tail (rare)
            int r = col[rs[n] + k] & 0x1FFFF;
            unsigned v = *(const unsigned*)(p + r * 64 + c * 4);
            if (g == 0) {
                a0.x += __builtin_amdgcn_cvt_f32_fp8(v, 0);
                a0.y += __builtin_amdgcn_cvt_f32_fp8(v, 1);
                a0.z += __builtin_amdgcn_cvt_f32_fp8(v, 2);
                a0.w += __builtin_amdgcn_cvt_f32_fp8(v, 3);
            }
        }
        float sx = a0.x + a1.x, sy = a0.y + a1.y, sz = a0.z + a1.z, sw = a0.w + a1.w;
        // combine across the 4 row-groups (lanes {L, L^16, L^32, L^48})
        sx += __shfl_xor(sx, 16, 64); sx += __shfl_xor(sx, 32, 64);
        sy += __shfl_xor(sy, 16, 64); sy += __shfl_xor(sy, 32, 64);
        sz += __shfl_xor(sz, 16, 64); sz += __shfl_xor(sz, 32, 64);
        sw += __shfl_xor(sw, 16, 64); sw += __shfl_xor(sw, 32, 64);

        float inv = 1.0f / fmaxf((float)dg, 1.0f);
        ushort4 qv = *(const ushort4*)(q + node * 64 + c * 4);
        float h0 = fmaxf(sx * inv + b2v.x + bf2f(qv.x), 0.f);
        float h1 = fmaxf(sy * inv + b2v.y + bf2f(qv.y), 0.f);
        float h2 = fmaxf(sz * inv + b2v.z + bf2f(qv.z), 0.f);
        float h3 = fmaxf(sw * inv + b2v.w + bf2f(qv.w), 0.f);

        float p0 = h0 * w01.x + h1 * w01.z + h2 * w23.x + h3 * w23.z;
        float p1 = h0 * w01.y + h1 * w01.w + h2 * w23.y + h3 * w23.w;
        if (g != 0) { p0 = 0.f; p1 = 0.f; }             // groups duplicate
        p0 += __shfl_down(p0, 8, 64);  p1 += __shfl_down(p1, 8, 64);
        p0 += __shfl_down(p0, 4, 64);  p1 += __shfl_down(p1, 4, 64);
        p0 += __shfl_down(p0, 2, 64);  p1 += __shfl_down(p1, 2, 64);
        p0 += __shfl_down(p0, 1, 64);  p1 += __shfl_down(p1, 1, 64);
        if (lane == 0) {
            int grp = batch[node];
            atomicAdd(&gsum[grp * 2 + 0], p0);
            atomicAdd(&gsum[grp * 2 + 1], p1);
        }
    }
}

// ---------------- finalize: out = gsum/cnt + bout ----------------
__global__ __launch_bounds__(256) void finalize_kernel(
    const float* __restrict__ gsum, const int* __restrict__ gstart,
    const float* __restrict__ bout, float* __restrict__ out)
{
    int g = blockIdx.x * 256 + threadIdx.x;
    if (g >= N_GRAPHS) return;
    int cnt = gstart[g + 1] - gstart[g];
    float inv = 1.0f / fmaxf((float)cnt, 1.0f);
    out[g * 2 + 0] = gsum[g * 2 + 0] * inv + bout[0];
    out[g * 2 + 1] = gsum[g * 2 + 1] * inv + bout[1];
}

extern "C" void kernel_launch(void* const* d_in, const int* in_sizes, int n_in,
                              void* d_out, int out_size, void* d_ws, size_t ws_size,
                              hipStream_t stream) {
    const int*   x    = (const int*)  d_in[0];
    const int*   ei   = (const int*)  d_in[1];
    const int*   batch= (const int*)  d_in[2];
    const float* emb  = (const float*)d_in[3];
    const float* W1l  = (const float*)d_in[4];
    const float* b1   = (const float*)d_in[5];
    const float* W1r  = (const float*)d_in[6];
    const float* W2l  = (const float*)d_in[7];
    const float* b2   = (const float*)d_in[8];
    const float* W2r  = (const float*)d_in[9];
    const float* Wout = (const float*)d_in[10];
    const float* bout = (const float*)d_in[11];
    float* out = (float*)d_out;

    const int* src = ei;
    const int* dst = ei + N_EDGES;

    char* ws = (char*)d_ws;
    size_t off = 0;
    unsigned char*  p8     = (unsigned char*) (ws + off); off += (size_t)N_NODES * 64;      // 6.4 MB
    unsigned short* q16    = (unsigned short*)(ws + off); off += (size_t)N_NODES * 64 * 2;  // 12.8 MB
    unsigned short* w2frag = (unsigned short*)(ws + off); off += (size_t)8192 * 2;
    float*    embW1l = (float*)   (ws + off); off += (size_t)VOCAB * 64 * 4;
    float*    embW1r = (float*)   (ws + off); off += (size_t)VOCAB * 64 * 4;
    int*      rowst  = (int*)     (ws + off); off += (size_t)N_NODES * 4;
    int*      deg    = (int*)     (ws + off); off += (size_t)N_NODES * 4;
    int*      col    = (int*)     (ws + off); off += (size_t)(NBK * CAP + 256) * 4;   // 6.4 MB
    unsigned* edge8  = (unsigned*)(ws + off); off += (size_t)NBK * CAP * 4;           // 6.4 MB
    int*      gstart = (int*)     (ws + off); off += (size_t)(N_GRAPHS + 1) * 4;
    // contiguous zero region: cursor | gsum (one memset)
    int*      cursor = (int*)     (ws + off); off += (size_t)NBK * 4;
    float*    gsum   = (float*)   (ws + off); off += (size_t)N_GRAPHS * 2 * 4;

    hipMemsetAsync(cursor, 0, (size_t)NBK * 4 + (size_t)N_GRAPHS * 2 * 4, stream);

    scatter_kernel<<<SCAT_BLOCKS + GB + 32, 256, 0, stream>>>(
        src, dst, x, cursor, edge8,
        batch, gstart, emb, W1l, W1r, W2l, W2r, embW1l, embW1r, w2frag);
    csr_kernel<<<NBK, 256, 0, stream>>>(edge8, cursor, rowst, deg, col);
    sage1_kernel<<<N_NODES / (4 * S1_NPW), 256, 0, stream>>>(
        x, embW1l, embW1r, b1, rowst, deg, col, w2frag, p8, q16);
    sage2_kernel<<<N_NODES / (4 * S2_NPW), 256, 0, stream>>>(
        p8, q16, rowst, deg, col, b2, Wout, batch, gsum);
    finalize_kernel<<<(N_GRAPHS + 255) / 256, 256, 0, stream>>>(gsum, gstart, bout, out);
}